// Round 1
// baseline (3531.078 us; speedup 1.0000x reference)
//
#include <hip/hip_runtime.h>

#define BB 2
#define LL 5000
#define DM 512
#define DI 1024
#define DSz 64
#define DRr 32
#define NXx 160
#define ML (BB*LL)

__device__ __forceinline__ float siluf(float x) { return x / (1.0f + __expf(-x)); }
__device__ __forceinline__ float softplusf(float x) { return fmaxf(x, 0.0f) + log1pf(__expf(-fabsf(x))); }
__device__ __forceinline__ float seluf(float x) {
  const float sc = 1.0507009873554805f, al = 1.6732632423543772f;
  return x > 0.0f ? sc * x : sc * al * (__expf(x) - 1.0f);
}

// ---------------- k1: h[b,l,d] = sum_c x[b,c,l] * w_init[d,c] ----------------
__global__ __launch_bounds__(512) void init_h_kernel(
    const float* __restrict__ x, const float* __restrict__ w_init, float* __restrict__ h)
{
  int il = blockIdx.x;              // b*LL + l
  int b = il / LL, l = il - b * LL;
  int dd = threadIdx.x;             // 0..511
  const float* xp = x + (size_t)b * 12 * LL + l;
  float acc = 0.f;
#pragma unroll
  for (int c = 0; c < 12; ++c) acc = fmaf(xp[(size_t)c * LL], w_init[dd * 12 + c], acc);
  h[(size_t)il * DM + dd] = acc;
}

// ---------------- generic GEMM: C[i,j] = act(sum_k A[i,k]*Bw[j,k] + bias[j]) ----------------
// ACT: 0 none, 1 selu, 2 softplus. 128x128 tile, BK=16, 256 threads, 8x8 per thread.
template<int ACT>
__global__ __launch_bounds__(256) void gemm_nt(
    const float* __restrict__ A, const float* __restrict__ Bw,
    const float* __restrict__ bias, float* __restrict__ C,
    int M, int N, int K, int lda, int ldb)
{
  __shared__ float As[16][132];   // k-major: As[kk][row]
  __shared__ float Bs[16][132];
  int tid = threadIdx.x;
  int i0 = blockIdx.x * 128, j0 = blockIdx.y * 128;
  int tx = tid & 15, ty = tid >> 4;
  int lr = tid >> 2, lc = tid & 3;
  float acc[8][8];
#pragma unroll
  for (int u = 0; u < 8; ++u)
#pragma unroll
    for (int v = 0; v < 8; ++v) acc[u][v] = 0.f;

  for (int k0 = 0; k0 < K; k0 += 16) {
    __syncthreads();
#pragma unroll
    for (int hh = 0; hh < 2; ++hh) {
      int row = lr + 64 * hh;
      int gi = i0 + row;
      float4 va = make_float4(0.f, 0.f, 0.f, 0.f);
      if (gi < M) va = *reinterpret_cast<const float4*>(A + (size_t)gi * lda + k0 + lc * 4);
      As[lc * 4 + 0][row] = va.x; As[lc * 4 + 1][row] = va.y;
      As[lc * 4 + 2][row] = va.z; As[lc * 4 + 3][row] = va.w;
      int gj = j0 + row;
      float4 vb = make_float4(0.f, 0.f, 0.f, 0.f);
      if (gj < N) vb = *reinterpret_cast<const float4*>(Bw + (size_t)gj * ldb + k0 + lc * 4);
      Bs[lc * 4 + 0][row] = vb.x; Bs[lc * 4 + 1][row] = vb.y;
      Bs[lc * 4 + 2][row] = vb.z; Bs[lc * 4 + 3][row] = vb.w;
    }
    __syncthreads();
#pragma unroll
    for (int kk = 0; kk < 16; ++kk) {
      float4 a0 = *reinterpret_cast<const float4*>(&As[kk][8 * ty]);
      float4 a1 = *reinterpret_cast<const float4*>(&As[kk][8 * ty + 4]);
      float4 b0 = *reinterpret_cast<const float4*>(&Bs[kk][8 * tx]);
      float4 b1 = *reinterpret_cast<const float4*>(&Bs[kk][8 * tx + 4]);
      float av[8] = {a0.x, a0.y, a0.z, a0.w, a1.x, a1.y, a1.z, a1.w};
      float bv[8] = {b0.x, b0.y, b0.z, b0.w, b1.x, b1.y, b1.z, b1.w};
#pragma unroll
      for (int u = 0; u < 8; ++u)
#pragma unroll
        for (int v = 0; v < 8; ++v) acc[u][v] = fmaf(av[u], bv[v], acc[u][v]);
    }
  }

#pragma unroll
  for (int u = 0; u < 8; ++u) {
    int gi = i0 + 8 * ty + u;
    if (gi >= M) continue;
#pragma unroll
    for (int v = 0; v < 8; ++v) {
      int gj = j0 + 8 * tx + v;
      if (gj >= N) continue;
      float r = acc[u][v];
      if (bias) r += bias[gj];
      if (ACT == 1) r = seluf(r);
      if (ACT == 2) r = softplusf(r);
      C[(size_t)gi * N + gj] = r;
    }
  }
}

// ---------------- causal depthwise conv (k=4) + silu ----------------
__global__ __launch_bounds__(256) void conv_silu_kernel(
    const float* __restrict__ xi, const float* __restrict__ cw,
    const float* __restrict__ cb, float* __restrict__ xc)
{
  int il = blockIdx.x;              // b*LL + l
  int l = il % LL;
  int d = blockIdx.y * 256 + threadIdx.x;
  float acc = cb[d];
  if (l >= 3) acc = fmaf(xi[(size_t)(il - 3) * DI + d], cw[d * 4 + 0], acc);
  if (l >= 2) acc = fmaf(xi[(size_t)(il - 2) * DI + d], cw[d * 4 + 1], acc);
  if (l >= 1) acc = fmaf(xi[(size_t)(il - 1) * DI + d], cw[d * 4 + 2], acc);
  acc = fmaf(xi[(size_t)il * DI + d], cw[d * 4 + 3], acc);
  xc[(size_t)il * DI + d] = siluf(acc);
}

// ---------------- per-b transpose: in[R][Cc] (ld=ldin) -> out[Cc][R]; ACT=1 applies silu ----------------
template<int ACT>
__global__ __launch_bounds__(256) void transpose_k(
    const float* __restrict__ in, float* __restrict__ out,
    int R, int Cc, int ldin, long long bstr)
{
  __shared__ float tile[32][33];
  const float* ip = in + (size_t)blockIdx.z * bstr;
  float* op = out + (size_t)blockIdx.z * bstr;
  int r0 = blockIdx.x * 32, c0 = blockIdx.y * 32;
  int tx = threadIdx.x, ty2 = threadIdx.y;
#pragma unroll
  for (int i = ty2; i < 32; i += 8) {
    int r = r0 + i, c = c0 + tx;
    if (r < R && c < Cc) {
      float v = ip[(size_t)r * ldin + c];
      if (ACT == 1) v = siluf(v);
      tile[i][tx] = v;
    }
  }
  __syncthreads();
#pragma unroll
  for (int i = ty2; i < 32; i += 8) {
    int c = c0 + i, r = r0 + tx;
    if (r < R && c < Cc) op[(size_t)c * R + r] = tile[tx][i];
  }
}

// ---------------- selective scan: wave per (b,d), lane = state s ----------------
// yT[b,d,t] = (sum_s h_t[s]*C[b,t,s] + u*D[d]) * silu(z)[b,d,t]
__global__ __launch_bounds__(64) void scan_kernel(
    const float* __restrict__ dtT, const float* __restrict__ uT,
    const float* __restrict__ szT, const float* __restrict__ xdbl,
    const float* __restrict__ A_log, const float* __restrict__ Dv,
    float* __restrict__ yT)
{
  int bd = blockIdx.x;              // 0..2047
  int b = bd >> 10, d = bd & (DI - 1);
  int s = threadIdx.x;              // 0..63
  float Ac = -__expf(A_log[d * DSz + s]);
  float Dd = Dv[d];
  size_t base = (size_t)bd * LL;
  const float* pdt = dtT + base;
  const float* pu = uT + base;
  const float* psz = szT + base;
  float* py = yT + base;
  const float* pB = xdbl + (size_t)b * LL * NXx + DRr + s;  // B at cols [32,96), C at [96,160)
  float hst = 0.f;
#pragma unroll 4
  for (int t = 0; t < LL; ++t) {
    float dtv = pdt[t];
    float u = pu[t];
    float Bv = pB[0];
    float Cv = pB[DSz];
    pB += NXx;
    float dA = __expf(dtv * Ac);
    hst = fmaf(dA, hst, dtv * u * Bv);
    float p = hst * Cv;
#pragma unroll
    for (int mm = 32; mm >= 1; mm >>= 1) p += __shfl_xor(p, mm, 64);
    if (s == 0) py[t] = fmaf(u, Dd, p) * psz[t];
  }
}

// ---------------- o[b,c,l] = sum_j m[b,l,j]*w_final[c,j]; wave per (b,l) ----------------
__global__ __launch_bounds__(256) void out_proj_kernel(
    const float* __restrict__ m, const float* __restrict__ wf, float* __restrict__ o)
{
  int row = blockIdx.x * 4 + (threadIdx.x >> 6);  // b*LL + l
  int lane = threadIdx.x & 63;
  int b = row / LL, l = row - b * LL;
  const float* mp = m + (size_t)row * DM;
  float p[12];
#pragma unroll
  for (int c = 0; c < 12; ++c) p[c] = 0.f;
  for (int j0 = 0; j0 < DM; j0 += 64) {
    float mv = mp[j0 + lane];
#pragma unroll
    for (int c = 0; c < 12; ++c) p[c] = fmaf(mv, wf[c * DM + j0 + lane], p[c]);
  }
#pragma unroll
  for (int c = 0; c < 12; ++c) {
    float v = p[c];
#pragma unroll
    for (int mm = 32; mm >= 1; mm >>= 1) v += __shfl_xor(v, mm, 64);
    if (lane == 0) o[(size_t)b * 60000 + c * LL + l] = v;
  }
}

// ---------------- fc1: f1[b,i] = sum_idx o[b,idx]*w1[i,idx] + b1[i] ----------------
__global__ __launch_bounds__(256) void fc1_kernel(
    const float* __restrict__ o, const float* __restrict__ w1,
    const float* __restrict__ b1, float* __restrict__ f1)
{
  int i = blockIdx.x;               // 0..511
  int tid = threadIdx.x;
  const float* wr = w1 + (size_t)i * 60000;
  float a0 = 0.f, a1 = 0.f;
  for (int idx = tid; idx < 60000; idx += 256) {
    float w = wr[idx];
    a0 = fmaf(o[idx], w, a0);
    a1 = fmaf(o[60000 + idx], w, a1);
  }
#pragma unroll
  for (int mm = 32; mm >= 1; mm >>= 1) { a0 += __shfl_xor(a0, mm, 64); a1 += __shfl_xor(a1, mm, 64); }
  __shared__ float r0[4], r1[4];
  int w4 = tid >> 6;
  if ((tid & 63) == 0) { r0[w4] = a0; r1[w4] = a1; }
  __syncthreads();
  if (tid == 0) {
    float s0 = r0[0] + r0[1] + r0[2] + r0[3];
    float s1 = r1[0] + r1[1] + r1[2] + r1[3];
    f1[i] = s0 + b1[i];
    f1[512 + i] = s1 + b1[i];
  }
}

__global__ __launch_bounds__(64) void fc2_kernel(
    const float* __restrict__ f1, const float* __restrict__ w2,
    const float* __restrict__ b2, float* __restrict__ f2)
{
  int i = blockIdx.x;               // 0..255
  int lane = threadIdx.x;
  const float* wr = w2 + (size_t)i * 512;
  float a0 = 0.f, a1 = 0.f;
  for (int k = lane; k < 512; k += 64) {
    float w = wr[k];
    a0 = fmaf(f1[k], w, a0);
    a1 = fmaf(f1[512 + k], w, a1);
  }
#pragma unroll
  for (int mm = 32; mm >= 1; mm >>= 1) { a0 += __shfl_xor(a0, mm, 64); a1 += __shfl_xor(a1, mm, 64); }
  if (lane == 0) { f2[i] = a0 + b2[i]; f2[256 + i] = a1 + b2[i]; }
}

__global__ __launch_bounds__(64) void fc34_kernel(
    const float* __restrict__ f2, const float* __restrict__ w3, const float* __restrict__ b3,
    const float* __restrict__ w4, const float* __restrict__ b4, float* __restrict__ outp)
{
  __shared__ float f3[128];
  int t = threadIdx.x;              // 0..63
  float a0 = 0.f, a1 = 0.f;
  for (int k = 0; k < 256; ++k) {
    float w = w3[t * 256 + k];
    a0 = fmaf(f2[k], w, a0);
    a1 = fmaf(f2[256 + k], w, a1);
  }
  f3[t] = a0 + b3[t];
  f3[64 + t] = a1 + b3[t];
  __syncthreads();
  if (t < 16) {
    int b = t >> 3, i = t & 7;
    float a = b4[i];
    for (int k = 0; k < 64; ++k) a = fmaf(f3[b * 64 + k], w4[i * 64 + k], a);
    outp[b * 8 + i] = a;
  }
}

extern "C" void kernel_launch(void* const* d_in, const int* in_sizes, int n_in,
                              void* d_out, int out_size, void* d_ws, size_t ws_size,
                              hipStream_t stream)
{
  const float* x       = (const float*)d_in[0];
  const float* w_init  = (const float*)d_in[1];
  const float* w_final = (const float*)d_in[2];
  const float* w_in    = (const float*)d_in[3];
  const float* conv_w  = (const float*)d_in[4];
  const float* conv_b  = (const float*)d_in[5];
  const float* w_xproj = (const float*)d_in[6];
  const float* w_dt    = (const float*)d_in[7];
  const float* b_dt    = (const float*)d_in[8];
  const float* A_log   = (const float*)d_in[9];
  const float* Dv      = (const float*)d_in[10];
  const float* w_out   = (const float*)d_in[11];
  const float* w_fc1   = (const float*)d_in[12];
  const float* b_fc1   = (const float*)d_in[13];
  const float* w_fc2   = (const float*)d_in[14];
  const float* b_fc2   = (const float*)d_in[15];
  const float* w_fc3   = (const float*)d_in[16];
  const float* b_fc3   = (const float*)d_in[17];
  const float* w_fc4   = (const float*)d_in[18];
  const float* b_fc4   = (const float*)d_in[19];

  float* ws = (float*)d_ws;
  // arena (floats), with slot reuse:
  const size_t S7 = 0;                               // h  -> later m          (5,120,000)
  const size_t S1 = S7 + (size_t)ML * DM;            // xi -> dt_l -> yT       (10,240,000)
  const size_t S2 = S1 + (size_t)ML * DI;            // z  -> y_l
  const size_t S3 = S2 + (size_t)ML * DI;            // xc -> szT
  const size_t S4 = S3 + (size_t)ML * DI;            // dtT
  const size_t S5 = S4 + (size_t)ML * DI;            // xcT
  const size_t S8 = S5 + (size_t)ML * DI;            // xdbl (1,600,000)
  const size_t S9 = S8 + (size_t)ML * NXx;           // o (120,000)
  const size_t SF1 = S9 + 120000;                    // f1 (1024)
  const size_t SF2 = SF1 + 1024;                     // f2 (512)

  float* h    = ws + S7;
  float* xi   = ws + S1;
  float* z    = ws + S2;
  float* xc   = ws + S3;
  float* dtT  = ws + S4;
  float* xcT  = ws + S5;
  float* xdbl = ws + S8;
  float* dt_l = ws + S1;   // reuse xi slot (xi dead after conv)
  float* szT  = ws + S3;   // reuse xc slot (xc dead after gemm2 + transpose)
  float* yT   = ws + S1;   // reuse dt_l slot (dead after its transpose)
  float* y_l  = ws + S2;   // reuse z slot (dead after silu-transpose)
  float* mbuf = ws + S7;   // reuse h slot
  float* o    = ws + S9;
  float* f1   = ws + SF1;
  float* f2   = ws + SF2;

  const int GM = (ML + 127) / 128;   // 79
  dim3 tb(32, 8);

  init_h_kernel<<<ML, 512, 0, stream>>>(x, w_init, h);
  gemm_nt<0><<<dim3(GM, DI / 128), 256, 0, stream>>>(h, w_in, nullptr, xi, ML, DI, DM, DM, DM);
  gemm_nt<0><<<dim3(GM, DI / 128), 256, 0, stream>>>(h, w_in + (size_t)DI * DM, nullptr, z, ML, DI, DM, DM, DM);
  conv_silu_kernel<<<dim3(ML, DI / 256), 256, 0, stream>>>(xi, conv_w, conv_b, xc);
  gemm_nt<0><<<dim3(GM, 2), 256, 0, stream>>>(xc, w_xproj, nullptr, xdbl, ML, NXx, DI, DI, DI);
  gemm_nt<2><<<dim3(GM, DI / 128), 256, 0, stream>>>(xdbl, w_dt, b_dt, dt_l, ML, DI, DRr, NXx, DRr);
  transpose_k<0><<<dim3(157, 32, 2), tb, 0, stream>>>(dt_l, dtT, LL, DI, DI, (long long)LL * DI);
  transpose_k<0><<<dim3(157, 32, 2), tb, 0, stream>>>(xc, xcT, LL, DI, DI, (long long)LL * DI);
  transpose_k<1><<<dim3(157, 32, 2), tb, 0, stream>>>(z, szT, LL, DI, DI, (long long)LL * DI);
  scan_kernel<<<BB * DI, 64, 0, stream>>>(dtT, xcT, szT, xdbl, A_log, Dv, yT);
  transpose_k<0><<<dim3(32, 157, 2), tb, 0, stream>>>(yT, y_l, DI, LL, LL, (long long)LL * DI);
  gemm_nt<1><<<dim3(GM, DM / 128), 256, 0, stream>>>(y_l, w_out, nullptr, mbuf, ML, DM, DI, DI, DI);
  out_proj_kernel<<<ML / 4, 256, 0, stream>>>(mbuf, w_final, o);
  fc1_kernel<<<512, 256, 0, stream>>>(o, w_fc1, b_fc1, f1);
  fc2_kernel<<<256, 64, 0, stream>>>(f1, w_fc2, b_fc2, f2);
  fc34_kernel<<<1, 64, 0, stream>>>(f2, w_fc3, b_fc3, w_fc4, b_fc4, (float*)d_out);
}

// Round 4
// 2060.370 us; speedup vs baseline: 1.7138x; 1.7138x over previous
//
#include <hip/hip_runtime.h>

#define BB 2
#define LL 5000
#define DM 512
#define DI 1024
#define DSz 64
#define DRr 32
#define NXx 160
#define ML (BB*LL)
#define NC 25
#define LC 200

__device__ __forceinline__ float siluf(float x) { return x / (1.0f + __expf(-x)); }
__device__ __forceinline__ float softplusf(float x) { return fmaxf(x, 0.0f) + log1pf(__expf(-fabsf(x))); }
__device__ __forceinline__ float seluf(float x) {
  const float sc = 1.0507009873554805f, al = 1.6732632423543772f;
  return x > 0.0f ? sc * x : sc * al * (__expf(x) - 1.0f);
}

// ---------------- k1: h[b,l,d] = sum_c x[b,c,l] * w_init[d,c] ----------------
__global__ __launch_bounds__(512) void init_h_kernel(
    const float* __restrict__ x, const float* __restrict__ w_init, float* __restrict__ h)
{
  int il = blockIdx.x;              // b*LL + l
  int b = il / LL, l = il - b * LL;
  int dd = threadIdx.x;             // 0..511
  const float* xp = x + (size_t)b * 12 * LL + l;
  float acc = 0.f;
#pragma unroll
  for (int c = 0; c < 12; ++c) acc = fmaf(xp[(size_t)c * LL], w_init[dd * 12 + c], acc);
  h[(size_t)il * DM + dd] = acc;
}

// ---------------- generic GEMM: C[i,j] = act(sum_k A[i,k]*Bw[j,k] + bias[j]) ----------------
template<int ACT>
__global__ __launch_bounds__(256) void gemm_nt(
    const float* __restrict__ A, const float* __restrict__ Bw,
    const float* __restrict__ bias, float* __restrict__ C,
    int M, int N, int K, int lda, int ldb)
{
  __shared__ float As[16][132];   // k-major: As[kk][row]
  __shared__ float Bs[16][132];
  int tid = threadIdx.x;
  int i0 = blockIdx.x * 128, j0 = blockIdx.y * 128;
  int tx = tid & 15, ty = tid >> 4;
  int lr = tid >> 2, lc = tid & 3;
  float acc[8][8];
#pragma unroll
  for (int u = 0; u < 8; ++u)
#pragma unroll
    for (int v = 0; v < 8; ++v) acc[u][v] = 0.f;

  for (int k0 = 0; k0 < K; k0 += 16) {
    __syncthreads();
#pragma unroll
    for (int hh = 0; hh < 2; ++hh) {
      int row = lr + 64 * hh;
      int gi = i0 + row;
      float4 va = make_float4(0.f, 0.f, 0.f, 0.f);
      if (gi < M) va = *reinterpret_cast<const float4*>(A + (size_t)gi * lda + k0 + lc * 4);
      As[lc * 4 + 0][row] = va.x; As[lc * 4 + 1][row] = va.y;
      As[lc * 4 + 2][row] = va.z; As[lc * 4 + 3][row] = va.w;
      int gj = j0 + row;
      float4 vb = make_float4(0.f, 0.f, 0.f, 0.f);
      if (gj < N) vb = *reinterpret_cast<const float4*>(Bw + (size_t)gj * ldb + k0 + lc * 4);
      Bs[lc * 4 + 0][row] = vb.x; Bs[lc * 4 + 1][row] = vb.y;
      Bs[lc * 4 + 2][row] = vb.z; Bs[lc * 4 + 3][row] = vb.w;
    }
    __syncthreads();
#pragma unroll
    for (int kk = 0; kk < 16; ++kk) {
      float4 a0 = *reinterpret_cast<const float4*>(&As[kk][8 * ty]);
      float4 a1 = *reinterpret_cast<const float4*>(&As[kk][8 * ty + 4]);
      float4 b0 = *reinterpret_cast<const float4*>(&Bs[kk][8 * tx]);
      float4 b1 = *reinterpret_cast<const float4*>(&Bs[kk][8 * tx + 4]);
      float av[8] = {a0.x, a0.y, a0.z, a0.w, a1.x, a1.y, a1.z, a1.w};
      float bv[8] = {b0.x, b0.y, b0.z, b0.w, b1.x, b1.y, b1.z, b1.w};
#pragma unroll
      for (int u = 0; u < 8; ++u)
#pragma unroll
        for (int v = 0; v < 8; ++v) acc[u][v] = fmaf(av[u], bv[v], acc[u][v]);
    }
  }

#pragma unroll
  for (int u = 0; u < 8; ++u) {
    int gi = i0 + 8 * ty + u;
    if (gi >= M) continue;
#pragma unroll
    for (int v = 0; v < 8; ++v) {
      int gj = j0 + 8 * tx + v;
      if (gj >= N) continue;
      float r = acc[u][v];
      if (bias) r += bias[gj];
      if (ACT == 1) r = seluf(r);
      if (ACT == 2) r = softplusf(r);
      C[(size_t)gi * N + gj] = r;
    }
  }
}

// ---------------- causal depthwise conv (k=4) + silu ----------------
__global__ __launch_bounds__(256) void conv_silu_kernel(
    const float* __restrict__ xi, const float* __restrict__ cw,
    const float* __restrict__ cb, float* __restrict__ xc)
{
  int il = blockIdx.x;              // b*LL + l
  int l = il % LL;
  int d = blockIdx.y * 256 + threadIdx.x;
  float acc = cb[d];
  if (l >= 3) acc = fmaf(xi[(size_t)(il - 3) * DI + d], cw[d * 4 + 0], acc);
  if (l >= 2) acc = fmaf(xi[(size_t)(il - 2) * DI + d], cw[d * 4 + 1], acc);
  if (l >= 1) acc = fmaf(xi[(size_t)(il - 1) * DI + d], cw[d * 4 + 2], acc);
  acc = fmaf(xi[(size_t)il * DI + d], cw[d * 4 + 3], acc);
  xc[(size_t)il * DI + d] = siluf(acc);
}

// ---------------- per-b transpose: in[R][Cc] (ld=ldin) -> out[Cc][R]; ACT=1 applies silu ----------------
template<int ACT>
__global__ __launch_bounds__(256) void transpose_k(
    const float* __restrict__ in, float* __restrict__ out,
    int R, int Cc, int ldin, long long bstr)
{
  __shared__ float tile[32][33];
  const float* ip = in + (size_t)blockIdx.z * bstr;
  float* op = out + (size_t)blockIdx.z * bstr;
  int r0 = blockIdx.x * 32, c0 = blockIdx.y * 32;
  int tx = threadIdx.x, ty2 = threadIdx.y;
#pragma unroll
  for (int i = ty2; i < 32; i += 8) {
    int r = r0 + i, c = c0 + tx;
    if (r < R && c < Cc) {
      float v = ip[(size_t)r * ldin + c];
      if (ACT == 1) v = siluf(v);
      tile[i][tx] = v;
    }
  }
  __syncthreads();
#pragma unroll
  for (int i = ty2; i < 32; i += 8) {
    int c = c0 + i, r = r0 + tx;
    if (r < R && c < Cc) op[(size_t)c * R + r] = tile[tx][i];
  }
}

// ---------------- selective scan, chunked 2-stage ----------------
// stage 1: per (b,d,chunk) wave, lane=s: (prod a, h_partial) from h=0.
__global__ __launch_bounds__(256) void scan_part_kernel(
    const float* __restrict__ dtT, const float* __restrict__ uT,
    const float* __restrict__ xdbl, const float* __restrict__ A_log,
    float2* __restrict__ part)
{
  int task = blockIdx.x * 4 + (threadIdx.x >> 6);   // bd*NC + c
  int s = threadIdx.x & 63;
  int bd = task / NC, c = task - bd * NC;
  int b = bd >> 10, d = bd & (DI - 1);
  float Ac = -__expf(A_log[d * DSz + s]);
  size_t base = (size_t)bd * LL + c * LC;
  const float* pdt = dtT + base;
  const float* pu = uT + base;
  const float* pB = xdbl + ((size_t)b * LL + c * LC) * NXx + DRr + s;
  float h = 0.f, ap = 1.f;
#pragma unroll 4
  for (int t = 0; t < LC; ++t) {
    float dtv = pdt[t];
    float u = pu[t];
    float Bv = pB[0]; pB += NXx;
    float a = __expf(dtv * Ac);
    h = fmaf(a, h, dtv * u * Bv);
    ap *= a;
  }
  part[(size_t)task * DSz + s] = make_float2(ap, h);
}

// stage 2: per (b,d,chunk) wave: fold preceding partials -> carry-in, replay chunk, emit y.
// Butterfly batched 8 timesteps per pass for ILP.
__global__ __launch_bounds__(256) void scan_y_kernel(
    const float* __restrict__ dtT, const float* __restrict__ uT,
    const float* __restrict__ szT, const float* __restrict__ xdbl,
    const float* __restrict__ A_log, const float* __restrict__ Dv,
    const float2* __restrict__ part, float* __restrict__ yT)
{
  int task = blockIdx.x * 4 + (threadIdx.x >> 6);
  int s = threadIdx.x & 63;
  int bd = task / NC, c = task - bd * NC;
  int b = bd >> 10, d = bd & (DI - 1);
  float Ac = -__expf(A_log[d * DSz + s]);
  float Dd = Dv[d];

  // carry-in: fold partials of chunks 0..c-1 (ascending)
  float h = 0.f;
  const float2* pp = part + (size_t)bd * NC * DSz + s;
  for (int p = 0; p < c; ++p) {
    float2 v = pp[(size_t)p * DSz];
    h = fmaf(v.x, h, v.y);
  }

  size_t base = (size_t)bd * LL + c * LC;
  const float* pdt = dtT + base;
  const float* pu = uT + base;
  const float* psz = szT + base;
  float* py = yT + base;
  const float* pB = xdbl + ((size_t)b * LL + c * LC) * NXx + DRr + s;

  for (int t0 = 0; t0 < LC; t0 += 8) {
    float pr[8], uu[8], szv[8];
#pragma unroll
    for (int i = 0; i < 8; ++i) {
      float dtv = pdt[t0 + i];
      float u = pu[t0 + i];
      uu[i] = u;
      szv[i] = psz[t0 + i];
      float Bv = pB[0];
      float Cv = pB[DSz];
      pB += NXx;
      float a = __expf(dtv * Ac);
      h = fmaf(a, h, dtv * u * Bv);
      pr[i] = h * Cv;
    }
#pragma unroll
    for (int mm = 32; mm >= 1; mm >>= 1) {
#pragma unroll
      for (int i = 0; i < 8; ++i) pr[i] += __shfl_xor(pr[i], mm, 64);
    }
    if (s == 0) {
#pragma unroll
      for (int i = 0; i < 8; ++i) py[t0 + i] = fmaf(uu[i], Dd, pr[i]) * szv[i];
    }
  }
}

// ---------------- o[b,c,l] = sum_j m[b,l,j]*w_final[c,j]; wave per (b,l) ----------------
__global__ __launch_bounds__(256) void out_proj_kernel(
    const float* __restrict__ m, const float* __restrict__ wf, float* __restrict__ o)
{
  int row = blockIdx.x * 4 + (threadIdx.x >> 6);  // b*LL + l
  int lane = threadIdx.x & 63;
  int b = row / LL, l = row - b * LL;
  const float* mp = m + (size_t)row * DM;
  float p[12];
#pragma unroll
  for (int c = 0; c < 12; ++c) p[c] = 0.f;
  for (int j0 = 0; j0 < DM; j0 += 64) {
    float mv = mp[j0 + lane];
#pragma unroll
    for (int c = 0; c < 12; ++c) p[c] = fmaf(mv, wf[c * DM + j0 + lane], p[c]);
  }
#pragma unroll
  for (int c = 0; c < 12; ++c) {
    float v = p[c];
#pragma unroll
    for (int mm = 32; mm >= 1; mm >>= 1) v += __shfl_xor(v, mm, 64);
    if (lane == 0) o[(size_t)b * 60000 + c * LL + l] = v;
  }
}

// ---------------- fc1 ----------------
__global__ __launch_bounds__(256) void fc1_kernel(
    const float* __restrict__ o, const float* __restrict__ w1,
    const float* __restrict__ b1, float* __restrict__ f1)
{
  int i = blockIdx.x;               // 0..511
  int tid = threadIdx.x;
  const float* wr = w1 + (size_t)i * 60000;
  float a0 = 0.f, a1 = 0.f;
  for (int idx = tid; idx < 60000; idx += 256) {
    float w = wr[idx];
    a0 = fmaf(o[idx], w, a0);
    a1 = fmaf(o[60000 + idx], w, a1);
  }
#pragma unroll
  for (int mm = 32; mm >= 1; mm >>= 1) { a0 += __shfl_xor(a0, mm, 64); a1 += __shfl_xor(a1, mm, 64); }
  __shared__ float r0[4], r1[4];
  int w4 = tid >> 6;
  if ((tid & 63) == 0) { r0[w4] = a0; r1[w4] = a1; }
  __syncthreads();
  if (tid == 0) {
    float s0 = r0[0] + r0[1] + r0[2] + r0[3];
    float s1 = r1[0] + r1[1] + r1[2] + r1[3];
    f1[i] = s0 + b1[i];
    f1[512 + i] = s1 + b1[i];
  }
}

__global__ __launch_bounds__(64) void fc2_kernel(
    const float* __restrict__ f1, const float* __restrict__ w2,
    const float* __restrict__ b2, float* __restrict__ f2)
{
  int i = blockIdx.x;               // 0..255
  int lane = threadIdx.x;
  const float* wr = w2 + (size_t)i * 512;
  float a0 = 0.f, a1 = 0.f;
  for (int k = lane; k < 512; k += 64) {
    float w = wr[k];
    a0 = fmaf(f1[k], w, a0);
    a1 = fmaf(f1[512 + k], w, a1);
  }
#pragma unroll
  for (int mm = 32; mm >= 1; mm >>= 1) { a0 += __shfl_xor(a0, mm, 64); a1 += __shfl_xor(a1, mm, 64); }
  if (lane == 0) { f2[i] = a0 + b2[i]; f2[256 + i] = a1 + b2[i]; }
}

__global__ __launch_bounds__(64) void fc34_kernel(
    const float* __restrict__ f2, const float* __restrict__ w3, const float* __restrict__ b3,
    const float* __restrict__ w4, const float* __restrict__ b4, float* __restrict__ outp)
{
  __shared__ float f3[128];
  int t = threadIdx.x;              // 0..63
  float a0 = 0.f, a1 = 0.f;
  for (int k = 0; k < 256; ++k) {
    float w = w3[t * 256 + k];
    a0 = fmaf(f2[k], w, a0);
    a1 = fmaf(f2[256 + k], w, a1);
  }
  f3[t] = a0 + b3[t];
  f3[64 + t] = a1 + b3[t];
  __syncthreads();
  if (t < 16) {
    int b = t >> 3, i = t & 7;
    float a = b4[i];
    for (int k = 0; k < 64; ++k) a = fmaf(f3[b * 64 + k], w4[i * 64 + k], a);
    outp[b * 8 + i] = a;
  }
}

extern "C" void kernel_launch(void* const* d_in, const int* in_sizes, int n_in,
                              void* d_out, int out_size, void* d_ws, size_t ws_size,
                              hipStream_t stream)
{
  const float* x       = (const float*)d_in[0];
  const float* w_init  = (const float*)d_in[1];
  const float* w_final = (const float*)d_in[2];
  const float* w_in    = (const float*)d_in[3];
  const float* conv_w  = (const float*)d_in[4];
  const float* conv_b  = (const float*)d_in[5];
  const float* w_xproj = (const float*)d_in[6];
  const float* w_dt    = (const float*)d_in[7];
  const float* b_dt    = (const float*)d_in[8];
  const float* A_log   = (const float*)d_in[9];
  const float* Dv      = (const float*)d_in[10];
  const float* w_out   = (const float*)d_in[11];
  const float* w_fc1   = (const float*)d_in[12];
  const float* b_fc1   = (const float*)d_in[13];
  const float* w_fc2   = (const float*)d_in[14];
  const float* b_fc2   = (const float*)d_in[15];
  const float* w_fc3   = (const float*)d_in[16];
  const float* b_fc3   = (const float*)d_in[17];
  const float* w_fc4   = (const float*)d_in[18];
  const float* b_fc4   = (const float*)d_in[19];

  float* ws = (float*)d_ws;
  const size_t S7 = 0;                               // h  -> later m
  const size_t S1 = S7 + (size_t)ML * DM;            // xi -> dt_l -> yT
  const size_t S2 = S1 + (size_t)ML * DI;            // z  -> part -> y_l
  const size_t S3 = S2 + (size_t)ML * DI;            // xc -> szT
  const size_t S4 = S3 + (size_t)ML * DI;            // dtT
  const size_t S5 = S4 + (size_t)ML * DI;            // xcT
  const size_t S8 = S5 + (size_t)ML * DI;            // xdbl
  const size_t S9 = S8 + (size_t)ML * NXx;           // o
  const size_t SF1 = S9 + 120000;                    // f1
  const size_t SF2 = SF1 + 1024;                     // f2

  float* h    = ws + S7;
  float* xi   = ws + S1;
  float* z    = ws + S2;
  float* xc   = ws + S3;
  float* dtT  = ws + S4;
  float* xcT  = ws + S5;
  float* xdbl = ws + S8;
  float* dt_l = ws + S1;   // reuse xi slot (xi dead after conv)
  float* szT  = ws + S3;   // reuse xc slot (xc dead after gemm2 + transpose)
  float2* part = (float2*)(ws + S2);  // reuse z slot (z dead after silu-transpose)
  float* yT   = ws + S1;   // reuse dt_l slot (dead after its transpose)
  float* y_l  = ws + S2;   // reuse part slot (dead after scan_y)
  float* mbuf = ws + S7;   // reuse h slot
  float* o    = ws + S9;
  float* f1   = ws + SF1;
  float* f2   = ws + SF2;

  const int GM = (ML + 127) / 128;   // 79
  dim3 tb(32, 8);

  init_h_kernel<<<ML, 512, 0, stream>>>(x, w_init, h);
  gemm_nt<0><<<dim3(GM, DI / 128), 256, 0, stream>>>(h, w_in, nullptr, xi, ML, DI, DM, DM, DM);
  gemm_nt<0><<<dim3(GM, DI / 128), 256, 0, stream>>>(h, w_in + (size_t)DI * DM, nullptr, z, ML, DI, DM, DM, DM);
  conv_silu_kernel<<<dim3(ML, DI / 256), 256, 0, stream>>>(xi, conv_w, conv_b, xc);
  gemm_nt<0><<<dim3(GM, 2), 256, 0, stream>>>(xc, w_xproj, nullptr, xdbl, ML, NXx, DI, DI, DI);
  gemm_nt<2><<<dim3(GM, DI / 128), 256, 0, stream>>>(xdbl, w_dt, b_dt, dt_l, ML, DI, DRr, NXx, DRr);
  transpose_k<0><<<dim3(157, 32, 2), tb, 0, stream>>>(dt_l, dtT, LL, DI, DI, (long long)LL * DI);
  transpose_k<0><<<dim3(157, 32, 2), tb, 0, stream>>>(xc, xcT, LL, DI, DI, (long long)LL * DI);
  transpose_k<1><<<dim3(157, 32, 2), tb, 0, stream>>>(z, szT, LL, DI, DI, (long long)LL * DI);
  scan_part_kernel<<<(BB * DI * NC) / 4, 256, 0, stream>>>(dtT, xcT, xdbl, A_log, part);
  scan_y_kernel<<<(BB * DI * NC) / 4, 256, 0, stream>>>(dtT, xcT, szT, xdbl, A_log, Dv, part, yT);
  transpose_k<0><<<dim3(32, 157, 2), tb, 0, stream>>>(yT, y_l, DI, LL, LL, (long long)LL * DI);
  gemm_nt<1><<<dim3(GM, DM / 128), 256, 0, stream>>>(y_l, w_out, nullptr, mbuf, ML, DM, DI, DI, DI);
  out_proj_kernel<<<ML / 4, 256, 0, stream>>>(mbuf, w_final, o);
  fc1_kernel<<<512, 256, 0, stream>>>(o, w_fc1, b_fc1, f1);
  fc2_kernel<<<256, 64, 0, stream>>>(f1, w_fc2, b_fc2, f2);
  fc34_kernel<<<1, 64, 0, stream>>>(f2, w_fc3, b_fc3, w_fc4, b_fc4, (float*)d_out);
}

// Round 5
// 1615.904 us; speedup vs baseline: 2.1852x; 1.2751x over previous
//
#include <hip/hip_runtime.h>

#define BB 2
#define LL 5000
#define DM 512
#define DI 1024
#define DSz 64
#define DRr 32
#define NXx 160
#define ML (BB*LL)
#define NC 25
#define LC 200

__device__ __forceinline__ float siluf(float x) { return x / (1.0f + __expf(-x)); }
__device__ __forceinline__ float softplusf(float x) { return fmaxf(x, 0.0f) + log1pf(__expf(-fabsf(x))); }
__device__ __forceinline__ float seluf(float x) {
  const float sc = 1.0507009873554805f, al = 1.6732632423543772f;
  return x > 0.0f ? sc * x : sc * al * (__expf(x) - 1.0f);
}

// ---------------- k1: h[b,l,d] = sum_c x[b,c,l] * w_init[d,c] ----------------
__global__ __launch_bounds__(512) void init_h_kernel(
    const float* __restrict__ x, const float* __restrict__ w_init, float* __restrict__ h)
{
  int il = blockIdx.x;              // b*LL + l
  int b = il / LL, l = il - b * LL;
  int dd = threadIdx.x;             // 0..511
  const float* xp = x + (size_t)b * 12 * LL + l;
  float acc = 0.f;
#pragma unroll
  for (int c = 0; c < 12; ++c) acc = fmaf(xp[(size_t)c * LL], w_init[dd * 12 + c], acc);
  h[(size_t)il * DM + dd] = acc;
}

// ---------------- generic GEMM: C[i,j] = act(sum_k A[i,k]*Bw[j,k] + bias[j]) ----------------
template<int ACT>
__global__ __launch_bounds__(256) void gemm_nt(
    const float* __restrict__ A, const float* __restrict__ Bw,
    const float* __restrict__ bias, float* __restrict__ C,
    int M, int N, int K, int lda, int ldb)
{
  __shared__ float As[16][132];   // k-major: As[kk][row]
  __shared__ float Bs[16][132];
  int tid = threadIdx.x;
  int i0 = blockIdx.x * 128, j0 = blockIdx.y * 128;
  int tx = tid & 15, ty = tid >> 4;
  int lr = tid >> 2, lc = tid & 3;
  float acc[8][8];
#pragma unroll
  for (int u = 0; u < 8; ++u)
#pragma unroll
    for (int v = 0; v < 8; ++v) acc[u][v] = 0.f;

  for (int k0 = 0; k0 < K; k0 += 16) {
    __syncthreads();
#pragma unroll
    for (int hh = 0; hh < 2; ++hh) {
      int row = lr + 64 * hh;
      int gi = i0 + row;
      float4 va = make_float4(0.f, 0.f, 0.f, 0.f);
      if (gi < M) va = *reinterpret_cast<const float4*>(A + (size_t)gi * lda + k0 + lc * 4);
      As[lc * 4 + 0][row] = va.x; As[lc * 4 + 1][row] = va.y;
      As[lc * 4 + 2][row] = va.z; As[lc * 4 + 3][row] = va.w;
      int gj = j0 + row;
      float4 vb = make_float4(0.f, 0.f, 0.f, 0.f);
      if (gj < N) vb = *reinterpret_cast<const float4*>(Bw + (size_t)gj * ldb + k0 + lc * 4);
      Bs[lc * 4 + 0][row] = vb.x; Bs[lc * 4 + 1][row] = vb.y;
      Bs[lc * 4 + 2][row] = vb.z; Bs[lc * 4 + 3][row] = vb.w;
    }
    __syncthreads();
#pragma unroll
    for (int kk = 0; kk < 16; ++kk) {
      float4 a0 = *reinterpret_cast<const float4*>(&As[kk][8 * ty]);
      float4 a1 = *reinterpret_cast<const float4*>(&As[kk][8 * ty + 4]);
      float4 b0 = *reinterpret_cast<const float4*>(&Bs[kk][8 * tx]);
      float4 b1 = *reinterpret_cast<const float4*>(&Bs[kk][8 * tx + 4]);
      float av[8] = {a0.x, a0.y, a0.z, a0.w, a1.x, a1.y, a1.z, a1.w};
      float bv[8] = {b0.x, b0.y, b0.z, b0.w, b1.x, b1.y, b1.z, b1.w};
#pragma unroll
      for (int u = 0; u < 8; ++u)
#pragma unroll
        for (int v = 0; v < 8; ++v) acc[u][v] = fmaf(av[u], bv[v], acc[u][v]);
    }
  }

#pragma unroll
  for (int u = 0; u < 8; ++u) {
    int gi = i0 + 8 * ty + u;
    if (gi >= M) continue;
#pragma unroll
    for (int v = 0; v < 8; ++v) {
      int gj = j0 + 8 * tx + v;
      if (gj >= N) continue;
      float r = acc[u][v];
      if (bias) r += bias[gj];
      if (ACT == 1) r = seluf(r);
      if (ACT == 2) r = softplusf(r);
      C[(size_t)gi * N + gj] = r;
    }
  }
}

// ---------------- causal depthwise conv (k=4) + silu ----------------
__global__ __launch_bounds__(256) void conv_silu_kernel(
    const float* __restrict__ xi, const float* __restrict__ cw,
    const float* __restrict__ cb, float* __restrict__ xc)
{
  int il = blockIdx.x;              // b*LL + l
  int l = il % LL;
  int d = blockIdx.y * 256 + threadIdx.x;
  float acc = cb[d];
  if (l >= 3) acc = fmaf(xi[(size_t)(il - 3) * DI + d], cw[d * 4 + 0], acc);
  if (l >= 2) acc = fmaf(xi[(size_t)(il - 2) * DI + d], cw[d * 4 + 1], acc);
  if (l >= 1) acc = fmaf(xi[(size_t)(il - 1) * DI + d], cw[d * 4 + 2], acc);
  acc = fmaf(xi[(size_t)il * DI + d], cw[d * 4 + 3], acc);
  xc[(size_t)il * DI + d] = siluf(acc);
}

// ---------------- per-b transpose: in[R][Cc] (ld=ldin) -> out[Cc][R]; ACT=1 applies silu ----------------
template<int ACT>
__global__ __launch_bounds__(256) void transpose_k(
    const float* __restrict__ in, float* __restrict__ out,
    int R, int Cc, int ldin, long long bstr)
{
  __shared__ float tile[32][33];
  const float* ip = in + (size_t)blockIdx.z * bstr;
  float* op = out + (size_t)blockIdx.z * bstr;
  int r0 = blockIdx.x * 32, c0 = blockIdx.y * 32;
  int tx = threadIdx.x, ty2 = threadIdx.y;
#pragma unroll
  for (int i = ty2; i < 32; i += 8) {
    int r = r0 + i, c = c0 + tx;
    if (r < R && c < Cc) {
      float v = ip[(size_t)r * ldin + c];
      if (ACT == 1) v = siluf(v);
      tile[i][tx] = v;
    }
  }
  __syncthreads();
#pragma unroll
  for (int i = ty2; i < 32; i += 8) {
    int c = c0 + i, r = r0 + tx;
    if (r < R && c < Cc) op[(size_t)c * R + r] = tile[tx][i];
  }
}

// ---------------- selective scan, chunked 2-stage, 4-states-per-lane ----------------
// Wave = 4 groups x 16 lanes. Group = one (bd,chunk) task. Lane j owns states 4j..4j+3.
// part[task*64 + s] = (prod_a, h_partial) for state s (layout unchanged vs prior round).

// stage 1: per-task partials from h=0. No cross-lane ops.
__global__ __launch_bounds__(256) void scan_part_kernel(
    const float* __restrict__ dtT, const float* __restrict__ uT,
    const float* __restrict__ xdbl, const float* __restrict__ A_log,
    float2* __restrict__ part)
{
  int task = (blockIdx.x * 256 + threadIdx.x) >> 4;   // bd*NC + c
  int j = threadIdx.x & 15;
  int bd = task / NC, c = task - bd * NC;
  int b = bd >> 10, d = bd & (DI - 1);
  float4 Al = *reinterpret_cast<const float4*>(A_log + d * DSz + 4 * j);
  float Ac0 = -__expf(Al.x), Ac1 = -__expf(Al.y), Ac2 = -__expf(Al.z), Ac3 = -__expf(Al.w);
  size_t base = (size_t)bd * LL + c * LC;
  const float* pdt = dtT + base;
  const float* pu = uT + base;
  const float4* pB4 = reinterpret_cast<const float4*>(
      xdbl + ((size_t)b * LL + c * LC) * NXx + DRr) + j;   // B block, 4 states
  float h0 = 0.f, h1 = 0.f, h2 = 0.f, h3 = 0.f;
  float ap0 = 1.f, ap1 = 1.f, ap2 = 1.f, ap3 = 1.f;
#pragma unroll 4
  for (int t = 0; t < LC; ++t) {
    float dtv = pdt[t];
    float u = pu[t];
    float4 Bv = pB4[0]; pB4 += NXx / 4;
    float du = dtv * u;
    float a0 = __expf(dtv * Ac0); h0 = fmaf(a0, h0, du * Bv.x); ap0 *= a0;
    float a1 = __expf(dtv * Ac1); h1 = fmaf(a1, h1, du * Bv.y); ap1 *= a1;
    float a2 = __expf(dtv * Ac2); h2 = fmaf(a2, h2, du * Bv.z); ap2 *= a2;
    float a3 = __expf(dtv * Ac3); h3 = fmaf(a3, h3, du * Bv.w); ap3 *= a3;
  }
  float4* pw = reinterpret_cast<float4*>(part + (size_t)task * DSz + 4 * j);
  pw[0] = make_float4(ap0, h0, ap1, h1);
  pw[1] = make_float4(ap2, h2, ap3, h3);
}

// stage 2: fold preceding partials -> carry-in, replay chunk, emit y.
// Reduction: 4 in-lane fmas + 4 xor rounds over 16 lanes; batched 8 timesteps.
__global__ __launch_bounds__(256) void scan_y_kernel(
    const float* __restrict__ dtT, const float* __restrict__ uT,
    const float* __restrict__ szT, const float* __restrict__ xdbl,
    const float* __restrict__ A_log, const float* __restrict__ Dv,
    const float2* __restrict__ part, float* __restrict__ yT)
{
  int task = (blockIdx.x * 256 + threadIdx.x) >> 4;
  int j = threadIdx.x & 15;
  int bd = task / NC, c = task - bd * NC;
  int b = bd >> 10, d = bd & (DI - 1);
  float4 Al = *reinterpret_cast<const float4*>(A_log + d * DSz + 4 * j);
  float Ac0 = -__expf(Al.x), Ac1 = -__expf(Al.y), Ac2 = -__expf(Al.z), Ac3 = -__expf(Al.w);
  float Dd = Dv[d];

  // carry-in: fold partials of chunks 0..c-1 (ascending)
  float h0 = 0.f, h1 = 0.f, h2 = 0.f, h3 = 0.f;
  const float4* pp = reinterpret_cast<const float4*>(part + (size_t)bd * NC * DSz) + 2 * j;
  for (int p = 0; p < c; ++p) {
    float4 v01 = pp[(size_t)p * (DSz / 2)];
    float4 v23 = pp[(size_t)p * (DSz / 2) + 1];
    h0 = fmaf(v01.x, h0, v01.y);
    h1 = fmaf(v01.z, h1, v01.w);
    h2 = fmaf(v23.x, h2, v23.y);
    h3 = fmaf(v23.z, h3, v23.w);
  }

  size_t base = (size_t)bd * LL + c * LC;
  const float* pdt = dtT + base;
  const float* pu = uT + base;
  const float* psz = szT + base;
  float* py = yT + base;
  const float4* pB4 = reinterpret_cast<const float4*>(
      xdbl + ((size_t)b * LL + c * LC) * NXx + DRr) + j;   // B; C is +16 float4s

  for (int t0 = 0; t0 < LC; t0 += 8) {
    float pr[8], uu[8], szv[8];
#pragma unroll
    for (int i = 0; i < 8; ++i) {
      float dtv = pdt[t0 + i];
      float u = pu[t0 + i];
      uu[i] = u;
      szv[i] = psz[t0 + i];
      float4 Bv = pB4[0];
      float4 Cv = pB4[DSz / 4];
      pB4 += NXx / 4;
      float du = dtv * u;
      float a0 = __expf(dtv * Ac0); h0 = fmaf(a0, h0, du * Bv.x);
      float a1 = __expf(dtv * Ac1); h1 = fmaf(a1, h1, du * Bv.y);
      float a2 = __expf(dtv * Ac2); h2 = fmaf(a2, h2, du * Bv.z);
      float a3 = __expf(dtv * Ac3); h3 = fmaf(a3, h3, du * Bv.w);
      float p = h0 * Cv.x;
      p = fmaf(h1, Cv.y, p);
      p = fmaf(h2, Cv.z, p);
      p = fmaf(h3, Cv.w, p);
      pr[i] = p;
    }
#pragma unroll
    for (int mm = 8; mm >= 1; mm >>= 1) {
#pragma unroll
      for (int i = 0; i < 8; ++i) pr[i] += __shfl_xor(pr[i], mm, 64);
    }
    if (j == 0) {
#pragma unroll
      for (int i = 0; i < 8; ++i) py[t0 + i] = fmaf(uu[i], Dd, pr[i]) * szv[i];
    }
  }
}

// ---------------- o[b,c,l] = sum_j m[b,l,j]*w_final[c,j]; wave per (b,l) ----------------
__global__ __launch_bounds__(256) void out_proj_kernel(
    const float* __restrict__ m, const float* __restrict__ wf, float* __restrict__ o)
{
  int row = blockIdx.x * 4 + (threadIdx.x >> 6);  // b*LL + l
  int lane = threadIdx.x & 63;
  int b = row / LL, l = row - b * LL;
  const float* mp = m + (size_t)row * DM;
  float p[12];
#pragma unroll
  for (int c = 0; c < 12; ++c) p[c] = 0.f;
  for (int j0 = 0; j0 < DM; j0 += 64) {
    float mv = mp[j0 + lane];
#pragma unroll
    for (int c = 0; c < 12; ++c) p[c] = fmaf(mv, wf[c * DM + j0 + lane], p[c]);
  }
#pragma unroll
  for (int c = 0; c < 12; ++c) {
    float v = p[c];
#pragma unroll
    for (int mm = 32; mm >= 1; mm >>= 1) v += __shfl_xor(v, mm, 64);
    if (lane == 0) o[(size_t)b * 60000 + c * LL + l] = v;
  }
}

// ---------------- fc1 ----------------
__global__ __launch_bounds__(256) void fc1_kernel(
    const float* __restrict__ o, const float* __restrict__ w1,
    const float* __restrict__ b1, float* __restrict__ f1)
{
  int i = blockIdx.x;               // 0..511
  int tid = threadIdx.x;
  const float* wr = w1 + (size_t)i * 60000;
  float a0 = 0.f, a1 = 0.f;
  for (int idx = tid; idx < 60000; idx += 256) {
    float w = wr[idx];
    a0 = fmaf(o[idx], w, a0);
    a1 = fmaf(o[60000 + idx], w, a1);
  }
#pragma unroll
  for (int mm = 32; mm >= 1; mm >>= 1) { a0 += __shfl_xor(a0, mm, 64); a1 += __shfl_xor(a1, mm, 64); }
  __shared__ float r0[4], r1[4];
  int w4 = tid >> 6;
  if ((tid & 63) == 0) { r0[w4] = a0; r1[w4] = a1; }
  __syncthreads();
  if (tid == 0) {
    float s0 = r0[0] + r0[1] + r0[2] + r0[3];
    float s1 = r1[0] + r1[1] + r1[2] + r1[3];
    f1[i] = s0 + b1[i];
    f1[512 + i] = s1 + b1[i];
  }
}

__global__ __launch_bounds__(64) void fc2_kernel(
    const float* __restrict__ f1, const float* __restrict__ w2,
    const float* __restrict__ b2, float* __restrict__ f2)
{
  int i = blockIdx.x;               // 0..255
  int lane = threadIdx.x;
  const float* wr = w2 + (size_t)i * 512;
  float a0 = 0.f, a1 = 0.f;
  for (int k = lane; k < 512; k += 64) {
    float w = wr[k];
    a0 = fmaf(f1[k], w, a0);
    a1 = fmaf(f1[512 + k], w, a1);
  }
#pragma unroll
  for (int mm = 32; mm >= 1; mm >>= 1) { a0 += __shfl_xor(a0, mm, 64); a1 += __shfl_xor(a1, mm, 64); }
  if (lane == 0) { f2[i] = a0 + b2[i]; f2[256 + i] = a1 + b2[i]; }
}

__global__ __launch_bounds__(64) void fc34_kernel(
    const float* __restrict__ f2, const float* __restrict__ w3, const float* __restrict__ b3,
    const float* __restrict__ w4, const float* __restrict__ b4, float* __restrict__ outp)
{
  __shared__ float f3[128];
  int t = threadIdx.x;              // 0..63
  float a0 = 0.f, a1 = 0.f;
  for (int k = 0; k < 256; ++k) {
    float w = w3[t * 256 + k];
    a0 = fmaf(f2[k], w, a0);
    a1 = fmaf(f2[256 + k], w, a1);
  }
  f3[t] = a0 + b3[t];
  f3[64 + t] = a1 + b3[t];
  __syncthreads();
  if (t < 16) {
    int b = t >> 3, i = t & 7;
    float a = b4[i];
    for (int k = 0; k < 64; ++k) a = fmaf(f3[b * 64 + k], w4[i * 64 + k], a);
    outp[b * 8 + i] = a;
  }
}

extern "C" void kernel_launch(void* const* d_in, const int* in_sizes, int n_in,
                              void* d_out, int out_size, void* d_ws, size_t ws_size,
                              hipStream_t stream)
{
  const float* x       = (const float*)d_in[0];
  const float* w_init  = (const float*)d_in[1];
  const float* w_final = (const float*)d_in[2];
  const float* w_in    = (const float*)d_in[3];
  const float* conv_w  = (const float*)d_in[4];
  const float* conv_b  = (const float*)d_in[5];
  const float* w_xproj = (const float*)d_in[6];
  const float* w_dt    = (const float*)d_in[7];
  const float* b_dt    = (const float*)d_in[8];
  const float* A_log   = (const float*)d_in[9];
  const float* Dv      = (const float*)d_in[10];
  const float* w_out   = (const float*)d_in[11];
  const float* w_fc1   = (const float*)d_in[12];
  const float* b_fc1   = (const float*)d_in[13];
  const float* w_fc2   = (const float*)d_in[14];
  const float* b_fc2   = (const float*)d_in[15];
  const float* w_fc3   = (const float*)d_in[16];
  const float* b_fc3   = (const float*)d_in[17];
  const float* w_fc4   = (const float*)d_in[18];
  const float* b_fc4   = (const float*)d_in[19];

  float* ws = (float*)d_ws;
  const size_t S7 = 0;                               // h  -> later m
  const size_t S1 = S7 + (size_t)ML * DM;            // xi -> dt_l -> yT
  const size_t S2 = S1 + (size_t)ML * DI;            // z  -> part -> y_l
  const size_t S3 = S2 + (size_t)ML * DI;            // xc -> szT
  const size_t S4 = S3 + (size_t)ML * DI;            // dtT
  const size_t S5 = S4 + (size_t)ML * DI;            // xcT
  const size_t S8 = S5 + (size_t)ML * DI;            // xdbl
  const size_t S9 = S8 + (size_t)ML * NXx;           // o
  const size_t SF1 = S9 + 120000;                    // f1
  const size_t SF2 = SF1 + 1024;                     // f2

  float* h    = ws + S7;
  float* xi   = ws + S1;
  float* z    = ws + S2;
  float* xc   = ws + S3;
  float* dtT  = ws + S4;
  float* xcT  = ws + S5;
  float* xdbl = ws + S8;
  float* dt_l = ws + S1;   // reuse xi slot (xi dead after conv)
  float* szT  = ws + S3;   // reuse xc slot (xc dead after gemm2 + transpose)
  float2* part = (float2*)(ws + S2);  // reuse z slot (z dead after silu-transpose)
  float* yT   = ws + S1;   // reuse dt_l slot (dead after its transpose)
  float* y_l  = ws + S2;   // reuse part slot (dead after scan_y)
  float* mbuf = ws + S7;   // reuse h slot
  float* o    = ws + S9;
  float* f1   = ws + SF1;
  float* f2   = ws + SF2;

  const int GM = (ML + 127) / 128;   // 79
  dim3 tb(32, 8);

  init_h_kernel<<<ML, 512, 0, stream>>>(x, w_init, h);
  gemm_nt<0><<<dim3(GM, DI / 128), 256, 0, stream>>>(h, w_in, nullptr, xi, ML, DI, DM, DM, DM);
  gemm_nt<0><<<dim3(GM, DI / 128), 256, 0, stream>>>(h, w_in + (size_t)DI * DM, nullptr, z, ML, DI, DM, DM, DM);
  conv_silu_kernel<<<dim3(ML, DI / 256), 256, 0, stream>>>(xi, conv_w, conv_b, xc);
  gemm_nt<0><<<dim3(GM, 2), 256, 0, stream>>>(xc, w_xproj, nullptr, xdbl, ML, NXx, DI, DI, DI);
  gemm_nt<2><<<dim3(GM, DI / 128), 256, 0, stream>>>(xdbl, w_dt, b_dt, dt_l, ML, DI, DRr, NXx, DRr);
  transpose_k<0><<<dim3(157, 32, 2), tb, 0, stream>>>(dt_l, dtT, LL, DI, DI, (long long)LL * DI);
  transpose_k<0><<<dim3(157, 32, 2), tb, 0, stream>>>(xc, xcT, LL, DI, DI, (long long)LL * DI);
  transpose_k<1><<<dim3(157, 32, 2), tb, 0, stream>>>(z, szT, LL, DI, DI, (long long)LL * DI);
  // 51200 tasks, 16 per 256-thread block
  scan_part_kernel<<<(BB * DI * NC) / 16, 256, 0, stream>>>(dtT, xcT, xdbl, A_log, part);
  scan_y_kernel<<<(BB * DI * NC) / 16, 256, 0, stream>>>(dtT, xcT, szT, xdbl, A_log, Dv, part, yT);
  transpose_k<0><<<dim3(32, 157, 2), tb, 0, stream>>>(yT, y_l, DI, LL, LL, (long long)LL * DI);
  gemm_nt<1><<<dim3(GM, DM / 128), 256, 0, stream>>>(y_l, w_out, nullptr, mbuf, ML, DM, DI, DI, DI);
  out_proj_kernel<<<ML / 4, 256, 0, stream>>>(mbuf, w_final, o);
  fc1_kernel<<<512, 256, 0, stream>>>(o, w_fc1, b_fc1, f1);
  fc2_kernel<<<256, 64, 0, stream>>>(f1, w_fc2, b_fc2, f2);
  fc34_kernel<<<1, 64, 0, stream>>>(f2, w_fc3, b_fc3, w_fc4, b_fc4, (float*)d_out);
}

// Round 6
// 1250.636 us; speedup vs baseline: 2.8234x; 1.2921x over previous
//
#include <hip/hip_runtime.h>

#define BB 2
#define LL 5000
#define DM 512
#define DI 1024
#define DSz 64
#define DRr 32
#define NXx 160
#define ML (BB*LL)
#define NC 25
#define LC 200

typedef short bf16x8 __attribute__((ext_vector_type(8)));
typedef float f32x4 __attribute__((ext_vector_type(4)));

__device__ __forceinline__ float siluf(float x) { return x / (1.0f + __expf(-x)); }
__device__ __forceinline__ float softplusf(float x) { return fmaxf(x, 0.0f) + log1pf(__expf(-fabsf(x))); }
__device__ __forceinline__ float seluf(float x) {
  const float sc = 1.0507009873554805f, al = 1.6732632423543772f;
  return x > 0.0f ? sc * x : sc * al * (__expf(x) - 1.0f);
}
__device__ __forceinline__ void bfsplit(float v, ushort& hi, ushort& lo) {
  unsigned u = __float_as_uint(v);
  unsigned h = (u + 0x7fffu + ((u >> 16) & 1u)) >> 16;
  hi = (ushort)h;
  float l = v - __uint_as_float(h << 16);
  unsigned ul = __float_as_uint(l);
  lo = (ushort)((ul + 0x7fffu + ((ul >> 16) & 1u)) >> 16);
}
__device__ __forceinline__ float bfrecon(ushort hi, ushort lo) {
  return __uint_as_float((unsigned)hi << 16) + __uint_as_float((unsigned)lo << 16);
}

// ---------------- weight fp32 -> (hi,lo) bf16 planes ----------------
__global__ __launch_bounds__(256) void cvt_split_kernel(
    const float* __restrict__ src, ushort* __restrict__ hi, ushort* __restrict__ lo, int n)
{
  int i = (blockIdx.x * 256 + threadIdx.x) * 4;
  if (i >= n) return;
  float4 v = *reinterpret_cast<const float4*>(src + i);
  ushort h0, l0, h1, l1, h2, l2, h3, l3;
  bfsplit(v.x, h0, l0); bfsplit(v.y, h1, l1);
  bfsplit(v.z, h2, l2); bfsplit(v.w, h3, l3);
  *reinterpret_cast<ushort4*>(hi + i) = make_ushort4(h0, h1, h2, h3);
  *reinterpret_cast<ushort4*>(lo + i) = make_ushort4(l0, l1, l2, l3);
}

// ---------------- k1: h[b,l,d] = sum_c x[b,c,l]*w_init[d,c], split output ----------------
__global__ __launch_bounds__(512) void init_h_split_kernel(
    const float* __restrict__ x, const float* __restrict__ w_init,
    ushort* __restrict__ hh, ushort* __restrict__ hl)
{
  int il = blockIdx.x;
  int b = il / LL, l = il - b * LL;
  int dd = threadIdx.x;
  const float* xp = x + (size_t)b * 12 * LL + l;
  float acc = 0.f;
#pragma unroll
  for (int c = 0; c < 12; ++c) acc = fmaf(xp[(size_t)c * LL], w_init[dd * 12 + c], acc);
  ushort h, lo; bfsplit(acc, h, lo);
  hh[(size_t)il * DM + dd] = h;
  hl[(size_t)il * DM + dd] = lo;
}

// ---------------- split-bf16 MFMA GEMM: C = act(Ahi+Alo)(Bhi+Blo)^T ----------------
// A[M][K], B[N][K] row-major bf16 planes. 128x128 tile, 4 waves (2x2), 16x16x32 MFMA,
// 3 MFMAs per product (hi*hi + lo*hi + hi*lo). SPLITN: cols [0,N/2)->C, [N/2,N)->C2.
template<int ACT, int SPLITN>
__global__ __launch_bounds__(256) void gemm_mfma(
    const ushort* __restrict__ Ahi, const ushort* __restrict__ Alo,
    const ushort* __restrict__ Bhi, const ushort* __restrict__ Blo,
    float* __restrict__ C, float* __restrict__ C2, int M, int N, int K)
{
  __shared__ ushort lds[4][128][40];   // planes: Ahi, Alo, Bhi, Blo; stride 40 (80B, 16B-aligned)
  int tid = threadIdx.x;
  int i0 = blockIdx.x * 128, j0 = blockIdx.y * 128;
  int l = tid & 63, wid = tid >> 6;
  int wm = (wid >> 1) * 64, wn = (wid & 1) * 64;
  int lr = l & 15, lk = (l >> 4) * 8;
  int sr = tid >> 1, kb = (tid & 1) * 16;

  f32x4 acc[4][4];
#pragma unroll
  for (int m = 0; m < 4; ++m)
#pragma unroll
    for (int n = 0; n < 4; ++n) acc[m][n] = (f32x4){0.f, 0.f, 0.f, 0.f};

  const uint4 z4 = make_uint4(0u, 0u, 0u, 0u);
  for (int k0 = 0; k0 < K; k0 += 32) {
    __syncthreads();
    {
      int gi = i0 + sr, gj = j0 + sr;
      size_t aoff = (size_t)gi * K + k0 + kb;
      size_t boff = (size_t)gj * K + k0 + kb;
      uint4 a0 = z4, a1 = z4, b0 = z4, b1 = z4, c0 = z4, c1 = z4, d0 = z4, d1 = z4;
      if (gi < M) {
        a0 = *reinterpret_cast<const uint4*>(Ahi + aoff);
        a1 = *reinterpret_cast<const uint4*>(Ahi + aoff + 8);
        b0 = *reinterpret_cast<const uint4*>(Alo + aoff);
        b1 = *reinterpret_cast<const uint4*>(Alo + aoff + 8);
      }
      if (gj < N) {
        c0 = *reinterpret_cast<const uint4*>(Bhi + boff);
        c1 = *reinterpret_cast<const uint4*>(Bhi + boff + 8);
        d0 = *reinterpret_cast<const uint4*>(Blo + boff);
        d1 = *reinterpret_cast<const uint4*>(Blo + boff + 8);
      }
      *reinterpret_cast<uint4*>(&lds[0][sr][kb]) = a0;
      *reinterpret_cast<uint4*>(&lds[0][sr][kb + 8]) = a1;
      *reinterpret_cast<uint4*>(&lds[1][sr][kb]) = b0;
      *reinterpret_cast<uint4*>(&lds[1][sr][kb + 8]) = b1;
      *reinterpret_cast<uint4*>(&lds[2][sr][kb]) = c0;
      *reinterpret_cast<uint4*>(&lds[2][sr][kb + 8]) = c1;
      *reinterpret_cast<uint4*>(&lds[3][sr][kb]) = d0;
      *reinterpret_cast<uint4*>(&lds[3][sr][kb + 8]) = d1;
    }
    __syncthreads();
    bf16x8 ah[4], av[4], bh[4], bv[4];
#pragma unroll
    for (int m = 0; m < 4; ++m) {
      ah[m] = *reinterpret_cast<const bf16x8*>(&lds[0][wm + m * 16 + lr][lk]);
      av[m] = *reinterpret_cast<const bf16x8*>(&lds[1][wm + m * 16 + lr][lk]);
    }
#pragma unroll
    for (int n = 0; n < 4; ++n) {
      bh[n] = *reinterpret_cast<const bf16x8*>(&lds[2][wn + n * 16 + lr][lk]);
      bv[n] = *reinterpret_cast<const bf16x8*>(&lds[3][wn + n * 16 + lr][lk]);
    }
#pragma unroll
    for (int m = 0; m < 4; ++m)
#pragma unroll
      for (int n = 0; n < 4; ++n) {
        acc[m][n] = __builtin_amdgcn_mfma_f32_16x16x32_bf16(ah[m], bh[n], acc[m][n], 0, 0, 0);
        acc[m][n] = __builtin_amdgcn_mfma_f32_16x16x32_bf16(av[m], bh[n], acc[m][n], 0, 0, 0);
        acc[m][n] = __builtin_amdgcn_mfma_f32_16x16x32_bf16(ah[m], bv[n], acc[m][n], 0, 0, 0);
      }
  }

#pragma unroll
  for (int m = 0; m < 4; ++m) {
    int r0 = i0 + wm + m * 16 + (l >> 4) * 4;
#pragma unroll
    for (int n = 0; n < 4; ++n) {
      int gc = j0 + wn + n * 16 + lr;
      if (gc >= N) continue;
#pragma unroll
      for (int q = 0; q < 4; ++q) {
        int gi = r0 + q;
        if (gi >= M) continue;
        float r = acc[m][n][q];
        if (ACT == 1) r = seluf(r);
        if (SPLITN) {
          int half = N >> 1;
          if (gc < half) C[(size_t)gi * half + gc] = r;
          else C2[(size_t)gi * half + (gc - half)] = r;
        } else {
          C[(size_t)gi * N + gc] = r;
        }
      }
    }
  }
}

// ---------------- fp32 SIMT GEMM (kept for dt: K=32) ----------------
template<int ACT>
__global__ __launch_bounds__(256) void gemm_nt(
    const float* __restrict__ A, const float* __restrict__ Bw,
    const float* __restrict__ bias, float* __restrict__ C,
    int M, int N, int K, int lda, int ldb)
{
  __shared__ float As[16][132];
  __shared__ float Bs[16][132];
  int tid = threadIdx.x;
  int i0 = blockIdx.x * 128, j0 = blockIdx.y * 128;
  int tx = tid & 15, ty = tid >> 4;
  int lr = tid >> 2, lc = tid & 3;
  float acc[8][8];
#pragma unroll
  for (int u = 0; u < 8; ++u)
#pragma unroll
    for (int v = 0; v < 8; ++v) acc[u][v] = 0.f;

  for (int k0 = 0; k0 < K; k0 += 16) {
    __syncthreads();
#pragma unroll
    for (int hh = 0; hh < 2; ++hh) {
      int row = lr + 64 * hh;
      int gi = i0 + row;
      float4 va = make_float4(0.f, 0.f, 0.f, 0.f);
      if (gi < M) va = *reinterpret_cast<const float4*>(A + (size_t)gi * lda + k0 + lc * 4);
      As[lc * 4 + 0][row] = va.x; As[lc * 4 + 1][row] = va.y;
      As[lc * 4 + 2][row] = va.z; As[lc * 4 + 3][row] = va.w;
      int gj = j0 + row;
      float4 vb = make_float4(0.f, 0.f, 0.f, 0.f);
      if (gj < N) vb = *reinterpret_cast<const float4*>(Bw + (size_t)gj * ldb + k0 + lc * 4);
      Bs[lc * 4 + 0][row] = vb.x; Bs[lc * 4 + 1][row] = vb.y;
      Bs[lc * 4 + 2][row] = vb.z; Bs[lc * 4 + 3][row] = vb.w;
    }
    __syncthreads();
#pragma unroll
    for (int kk = 0; kk < 16; ++kk) {
      float4 a0 = *reinterpret_cast<const float4*>(&As[kk][8 * ty]);
      float4 a1 = *reinterpret_cast<const float4*>(&As[kk][8 * ty + 4]);
      float4 b0 = *reinterpret_cast<const float4*>(&Bs[kk][8 * tx]);
      float4 b1 = *reinterpret_cast<const float4*>(&Bs[kk][8 * tx + 4]);
      float av[8] = {a0.x, a0.y, a0.z, a0.w, a1.x, a1.y, a1.z, a1.w};
      float bv[8] = {b0.x, b0.y, b0.z, b0.w, b1.x, b1.y, b1.z, b1.w};
#pragma unroll
      for (int u = 0; u < 8; ++u)
#pragma unroll
        for (int v = 0; v < 8; ++v) acc[u][v] = fmaf(av[u], bv[v], acc[u][v]);
    }
  }

#pragma unroll
  for (int u = 0; u < 8; ++u) {
    int gi = i0 + 8 * ty + u;
    if (gi >= M) continue;
#pragma unroll
    for (int v = 0; v < 8; ++v) {
      int gj = j0 + 8 * tx + v;
      if (gj >= N) continue;
      float r = acc[u][v];
      if (bias) r += bias[gj];
      if (ACT == 1) r = seluf(r);
      if (ACT == 2) r = softplusf(r);
      C[(size_t)gi * N + gj] = r;
    }
  }
}

// ---------------- causal depthwise conv (k=4) + silu, split output ----------------
__global__ __launch_bounds__(256) void conv_silu_split_kernel(
    const float* __restrict__ xi, const float* __restrict__ cw,
    const float* __restrict__ cb, ushort* __restrict__ xch, ushort* __restrict__ xcl)
{
  int il = blockIdx.x;
  int l = il % LL;
  int d = blockIdx.y * 256 + threadIdx.x;
  float acc = cb[d];
  if (l >= 3) acc = fmaf(xi[(size_t)(il - 3) * DI + d], cw[d * 4 + 0], acc);
  if (l >= 2) acc = fmaf(xi[(size_t)(il - 2) * DI + d], cw[d * 4 + 1], acc);
  if (l >= 1) acc = fmaf(xi[(size_t)(il - 1) * DI + d], cw[d * 4 + 2], acc);
  acc = fmaf(xi[(size_t)il * DI + d], cw[d * 4 + 3], acc);
  float v = siluf(acc);
  ushort h, lo; bfsplit(v, h, lo);
  xch[(size_t)il * DI + d] = h;
  xcl[(size_t)il * DI + d] = lo;
}

// ---------------- transposes ----------------
template<int ACT>
__global__ __launch_bounds__(256) void transpose_k(
    const float* __restrict__ in, float* __restrict__ out,
    int R, int Cc, int ldin, long long bstr)
{
  __shared__ float tile[32][33];
  const float* ip = in + (size_t)blockIdx.z * bstr;
  float* op = out + (size_t)blockIdx.z * bstr;
  int r0 = blockIdx.x * 32, c0 = blockIdx.y * 32;
  int tx = threadIdx.x, ty2 = threadIdx.y;
#pragma unroll
  for (int i = ty2; i < 32; i += 8) {
    int r = r0 + i, c = c0 + tx;
    if (r < R && c < Cc) {
      float v = ip[(size_t)r * ldin + c];
      if (ACT == 1) v = siluf(v);
      tile[i][tx] = v;
    }
  }
  __syncthreads();
#pragma unroll
  for (int i = ty2; i < 32; i += 8) {
    int c = c0 + i, r = r0 + tx;
    if (r < R && c < Cc) op[(size_t)c * R + r] = tile[tx][i];
  }
}

// hi/lo -> fp32 transpose (for xcT)
__global__ __launch_bounds__(256) void transpose_recon_k(
    const ushort* __restrict__ inhi, const ushort* __restrict__ inlo,
    float* __restrict__ out, int R, int Cc, int ldin, long long bstr)
{
  __shared__ float tile[32][33];
  const ushort* iph = inhi + (size_t)blockIdx.z * bstr;
  const ushort* ipl = inlo + (size_t)blockIdx.z * bstr;
  float* op = out + (size_t)blockIdx.z * bstr;
  int r0 = blockIdx.x * 32, c0 = blockIdx.y * 32;
  int tx = threadIdx.x, ty2 = threadIdx.y;
#pragma unroll
  for (int i = ty2; i < 32; i += 8) {
    int r = r0 + i, c = c0 + tx;
    if (r < R && c < Cc) {
      size_t idx = (size_t)r * ldin + c;
      tile[i][tx] = bfrecon(iph[idx], ipl[idx]);
    }
  }
  __syncthreads();
#pragma unroll
  for (int i = ty2; i < 32; i += 8) {
    int c = c0 + i, r = r0 + tx;
    if (r < R && c < Cc) op[(size_t)c * R + r] = tile[tx][i];
  }
}

// fp32 -> hi/lo transpose (for y)
__global__ __launch_bounds__(256) void transpose_split_k(
    const float* __restrict__ in, ushort* __restrict__ outhi, ushort* __restrict__ outlo,
    int R, int Cc, int ldin, long long bstr)
{
  __shared__ float tile[32][33];
  const float* ip = in + (size_t)blockIdx.z * bstr;
  ushort* oph = outhi + (size_t)blockIdx.z * bstr;
  ushort* opl = outlo + (size_t)blockIdx.z * bstr;
  int r0 = blockIdx.x * 32, c0 = blockIdx.y * 32;
  int tx = threadIdx.x, ty2 = threadIdx.y;
#pragma unroll
  for (int i = ty2; i < 32; i += 8) {
    int r = r0 + i, c = c0 + tx;
    if (r < R && c < Cc) tile[i][tx] = ip[(size_t)r * ldin + c];
  }
  __syncthreads();
#pragma unroll
  for (int i = ty2; i < 32; i += 8) {
    int c = c0 + i, r = r0 + tx;
    if (r < R && c < Cc) {
      ushort h, lo; bfsplit(tile[tx][i], h, lo);
      size_t idx = (size_t)c * R + r;
      oph[idx] = h; opl[idx] = lo;
    }
  }
}

// ---------------- selective scan, chunked 2-stage, 4-states-per-lane ----------------
__global__ __launch_bounds__(256) void scan_part_kernel(
    const float* __restrict__ dtT, const float* __restrict__ uT,
    const float* __restrict__ xdbl, const float* __restrict__ A_log,
    float2* __restrict__ part)
{
  int task = (blockIdx.x * 256 + threadIdx.x) >> 4;
  int j = threadIdx.x & 15;
  int bd = task / NC, c = task - bd * NC;
  int b = bd >> 10, d = bd & (DI - 1);
  float4 Al = *reinterpret_cast<const float4*>(A_log + d * DSz + 4 * j);
  float Ac0 = -__expf(Al.x), Ac1 = -__expf(Al.y), Ac2 = -__expf(Al.z), Ac3 = -__expf(Al.w);
  size_t base = (size_t)bd * LL + c * LC;
  const float* pdt = dtT + base;
  const float* pu = uT + base;
  const float4* pB4 = reinterpret_cast<const float4*>(
      xdbl + ((size_t)b * LL + c * LC) * NXx + DRr) + j;
  float h0 = 0.f, h1 = 0.f, h2 = 0.f, h3 = 0.f;
  float ap0 = 1.f, ap1 = 1.f, ap2 = 1.f, ap3 = 1.f;
#pragma unroll 4
  for (int t = 0; t < LC; ++t) {
    float dtv = pdt[t];
    float u = pu[t];
    float4 Bv = pB4[0]; pB4 += NXx / 4;
    float du = dtv * u;
    float a0 = __expf(dtv * Ac0); h0 = fmaf(a0, h0, du * Bv.x); ap0 *= a0;
    float a1 = __expf(dtv * Ac1); h1 = fmaf(a1, h1, du * Bv.y); ap1 *= a1;
    float a2 = __expf(dtv * Ac2); h2 = fmaf(a2, h2, du * Bv.z); ap2 *= a2;
    float a3 = __expf(dtv * Ac3); h3 = fmaf(a3, h3, du * Bv.w); ap3 *= a3;
  }
  float4* pw = reinterpret_cast<float4*>(part + (size_t)task * DSz + 4 * j);
  pw[0] = make_float4(ap0, h0, ap1, h1);
  pw[1] = make_float4(ap2, h2, ap3, h3);
}

__global__ __launch_bounds__(256) void scan_y_kernel(
    const float* __restrict__ dtT, const float* __restrict__ uT,
    const float* __restrict__ szT, const float* __restrict__ xdbl,
    const float* __restrict__ A_log, const float* __restrict__ Dv,
    const float2* __restrict__ part, float* __restrict__ yT)
{
  int task = (blockIdx.x * 256 + threadIdx.x) >> 4;
  int j = threadIdx.x & 15;
  int bd = task / NC, c = task - bd * NC;
  int b = bd >> 10, d = bd & (DI - 1);
  float4 Al = *reinterpret_cast<const float4*>(A_log + d * DSz + 4 * j);
  float Ac0 = -__expf(Al.x), Ac1 = -__expf(Al.y), Ac2 = -__expf(Al.z), Ac3 = -__expf(Al.w);
  float Dd = Dv[d];

  float h0 = 0.f, h1 = 0.f, h2 = 0.f, h3 = 0.f;
  const float4* pp = reinterpret_cast<const float4*>(part + (size_t)bd * NC * DSz) + 2 * j;
  for (int p = 0; p < c; ++p) {
    float4 v01 = pp[(size_t)p * (DSz / 2)];
    float4 v23 = pp[(size_t)p * (DSz / 2) + 1];
    h0 = fmaf(v01.x, h0, v01.y);
    h1 = fmaf(v01.z, h1, v01.w);
    h2 = fmaf(v23.x, h2, v23.y);
    h3 = fmaf(v23.z, h3, v23.w);
  }

  size_t base = (size_t)bd * LL + c * LC;
  const float* pdt = dtT + base;
  const float* pu = uT + base;
  const float* psz = szT + base;
  float* py = yT + base;
  const float4* pB4 = reinterpret_cast<const float4*>(
      xdbl + ((size_t)b * LL + c * LC) * NXx + DRr) + j;

  for (int t0 = 0; t0 < LC; t0 += 8) {
    float pr[8], uu[8], szv[8];
#pragma unroll
    for (int i = 0; i < 8; ++i) {
      float dtv = pdt[t0 + i];
      float u = pu[t0 + i];
      uu[i] = u;
      szv[i] = psz[t0 + i];
      float4 Bv = pB4[0];
      float4 Cv = pB4[DSz / 4];
      pB4 += NXx / 4;
      float du = dtv * u;
      float a0 = __expf(dtv * Ac0); h0 = fmaf(a0, h0, du * Bv.x);
      float a1 = __expf(dtv * Ac1); h1 = fmaf(a1, h1, du * Bv.y);
      float a2 = __expf(dtv * Ac2); h2 = fmaf(a2, h2, du * Bv.z);
      float a3 = __expf(dtv * Ac3); h3 = fmaf(a3, h3, du * Bv.w);
      float p = h0 * Cv.x;
      p = fmaf(h1, Cv.y, p);
      p = fmaf(h2, Cv.z, p);
      p = fmaf(h3, Cv.w, p);
      pr[i] = p;
    }
#pragma unroll
    for (int mm = 8; mm >= 1; mm >>= 1) {
#pragma unroll
      for (int i = 0; i < 8; ++i) pr[i] += __shfl_xor(pr[i], mm, 64);
    }
    if (j == 0) {
#pragma unroll
      for (int i = 0; i < 8; ++i) py[t0 + i] = fmaf(uu[i], Dd, pr[i]) * szv[i];
    }
  }
}

// ---------------- o[b,c,l] = sum_j m[b,l,j]*w_final[c,j]; wave per (b,l) ----------------
__global__ __launch_bounds__(256) void out_proj_kernel(
    const float* __restrict__ m, const float* __restrict__ wf, float* __restrict__ o)
{
  int row = blockIdx.x * 4 + (threadIdx.x >> 6);
  int lane = threadIdx.x & 63;
  int b = row / LL, l = row - b * LL;
  const float* mp = m + (size_t)row * DM;
  float p[12];
#pragma unroll
  for (int c = 0; c < 12; ++c) p[c] = 0.f;
  for (int j0 = 0; j0 < DM; j0 += 64) {
    float mv = mp[j0 + lane];
#pragma unroll
    for (int c = 0; c < 12; ++c) p[c] = fmaf(mv, wf[c * DM + j0 + lane], p[c]);
  }
#pragma unroll
  for (int c = 0; c < 12; ++c) {
    float v = p[c];
#pragma unroll
    for (int mm = 32; mm >= 1; mm >>= 1) v += __shfl_xor(v, mm, 64);
    if (lane == 0) o[(size_t)b * 60000 + c * LL + l] = v;
  }
}

// ---------------- fc chain ----------------
__global__ __launch_bounds__(256) void fc1_kernel(
    const float* __restrict__ o, const float* __restrict__ w1,
    const float* __restrict__ b1, float* __restrict__ f1)
{
  int i = blockIdx.x;
  int tid = threadIdx.x;
  const float* wr = w1 + (size_t)i * 60000;
  float a0 = 0.f, a1 = 0.f;
  for (int idx = tid; idx < 60000; idx += 256) {
    float w = wr[idx];
    a0 = fmaf(o[idx], w, a0);
    a1 = fmaf(o[60000 + idx], w, a1);
  }
#pragma unroll
  for (int mm = 32; mm >= 1; mm >>= 1) { a0 += __shfl_xor(a0, mm, 64); a1 += __shfl_xor(a1, mm, 64); }
  __shared__ float r0[4], r1[4];
  int w4 = tid >> 6;
  if ((tid & 63) == 0) { r0[w4] = a0; r1[w4] = a1; }
  __syncthreads();
  if (tid == 0) {
    f1[i] = r0[0] + r0[1] + r0[2] + r0[3] + b1[i];
    f1[512 + i] = r1[0] + r1[1] + r1[2] + r1[3] + b1[i];
  }
}

__global__ __launch_bounds__(64) void fc2_kernel(
    const float* __restrict__ f1, const float* __restrict__ w2,
    const float* __restrict__ b2, float* __restrict__ f2)
{
  int i = blockIdx.x;
  int lane = threadIdx.x;
  const float* wr = w2 + (size_t)i * 512;
  float a0 = 0.f, a1 = 0.f;
  for (int k = lane; k < 512; k += 64) {
    float w = wr[k];
    a0 = fmaf(f1[k], w, a0);
    a1 = fmaf(f1[512 + k], w, a1);
  }
#pragma unroll
  for (int mm = 32; mm >= 1; mm >>= 1) { a0 += __shfl_xor(a0, mm, 64); a1 += __shfl_xor(a1, mm, 64); }
  if (lane == 0) { f2[i] = a0 + b2[i]; f2[256 + i] = a1 + b2[i]; }
}

__global__ __launch_bounds__(64) void fc34_kernel(
    const float* __restrict__ f2, const float* __restrict__ w3, const float* __restrict__ b3,
    const float* __restrict__ w4, const float* __restrict__ b4, float* __restrict__ outp)
{
  __shared__ float f3[128];
  int t = threadIdx.x;
  float a0 = 0.f, a1 = 0.f;
  for (int k = 0; k < 256; ++k) {
    float w = w3[t * 256 + k];
    a0 = fmaf(f2[k], w, a0);
    a1 = fmaf(f2[256 + k], w, a1);
  }
  f3[t] = a0 + b3[t];
  f3[64 + t] = a1 + b3[t];
  __syncthreads();
  if (t < 16) {
    int b = t >> 3, i = t & 7;
    float a = b4[i];
    for (int k = 0; k < 64; ++k) a = fmaf(f3[b * 64 + k], w4[i * 64 + k], a);
    outp[b * 8 + i] = a;
  }
}

extern "C" void kernel_launch(void* const* d_in, const int* in_sizes, int n_in,
                              void* d_out, int out_size, void* d_ws, size_t ws_size,
                              hipStream_t stream)
{
  const float* x       = (const float*)d_in[0];
  const float* w_init  = (const float*)d_in[1];
  const float* w_final = (const float*)d_in[2];
  const float* w_in    = (const float*)d_in[3];
  const float* conv_w  = (const float*)d_in[4];
  const float* conv_b  = (const float*)d_in[5];
  const float* w_xproj = (const float*)d_in[6];
  const float* w_dt    = (const float*)d_in[7];
  const float* b_dt    = (const float*)d_in[8];
  const float* A_log   = (const float*)d_in[9];
  const float* Dv      = (const float*)d_in[10];
  const float* w_out   = (const float*)d_in[11];
  const float* w_fc1   = (const float*)d_in[12];
  const float* b_fc1   = (const float*)d_in[13];
  const float* w_fc2   = (const float*)d_in[14];
  const float* b_fc2   = (const float*)d_in[15];
  const float* w_fc3   = (const float*)d_in[16];
  const float* b_fc3   = (const float*)d_in[17];
  const float* w_fc4   = (const float*)d_in[18];
  const float* b_fc4   = (const float*)d_in[19];

  float* ws = (float*)d_ws;
  const size_t S7 = 0;                               // h_hi/h_lo -> later mbuf
  const size_t S1 = S7 + (size_t)ML * DM;            // xi -> dt_l -> yT
  const size_t S2 = S1 + (size_t)ML * DI;            // z -> part -> y_hi/y_lo
  const size_t S3 = S2 + (size_t)ML * DI;            // xc_hi/xc_lo -> szT
  const size_t S4 = S3 + (size_t)ML * DI;            // dtT
  const size_t S5 = S4 + (size_t)ML * DI;            // w hi/lo -> xcT -> wo hi/lo
  const size_t S8 = S5 + (size_t)ML * DI;            // xdbl
  const size_t S9 = S8 + (size_t)ML * NXx;           // o
  const size_t SF1 = S9 + 120000;
  const size_t SF2 = SF1 + 1024;

  ushort* h_hi = (ushort*)(ws + S7);
  ushort* h_lo = h_hi + (size_t)ML * DM;
  float*  xi   = ws + S1;
  float*  z    = ws + S2;
  ushort* xc_hi = (ushort*)(ws + S3);
  ushort* xc_lo = xc_hi + (size_t)ML * DI;
  float*  dtT  = ws + S4;
  float*  xcT  = ws + S5;
  float*  xdbl = ws + S8;
  float*  dt_l = ws + S1;
  float*  szT  = ws + S3;
  float2* part = (float2*)(ws + S2);
  float*  yT   = ws + S1;
  ushort* y_hi = (ushort*)(ws + S2);
  ushort* y_lo = y_hi + (size_t)ML * DI;
  float*  mbuf = ws + S7;
  float*  o    = ws + S9;
  float*  f1   = ws + SF1;
  float*  f2   = ws + SF2;

  ushort* wb    = (ushort*)(ws + S5);                // weights live in xcT slot pre-xcT
  ushort* wi_hi = wb;
  ushort* wi_lo = wb + (size_t)2048 * 512;
  ushort* wx_hi = wb + (size_t)2 * 2048 * 512;
  ushort* wx_lo = wx_hi + (size_t)160 * 1024;
  ushort* wo_hi = wb;                                // reused after xcT dead
  ushort* wo_lo = wb + (size_t)512 * 1024;

  const int GM = (ML + 127) / 128;   // 79
  dim3 tb(32, 8);

  cvt_split_kernel<<<1024, 256, 0, stream>>>(w_in, wi_hi, wi_lo, 2048 * 512);
  cvt_split_kernel<<<160, 256, 0, stream>>>(w_xproj, wx_hi, wx_lo, 160 * 1024);
  init_h_split_kernel<<<ML, 512, 0, stream>>>(x, w_init, h_hi, h_lo);
  gemm_mfma<0, 1><<<dim3(GM, 16), 256, 0, stream>>>(h_hi, h_lo, wi_hi, wi_lo, xi, z, ML, 2048, 512);
  conv_silu_split_kernel<<<dim3(ML, DI / 256), 256, 0, stream>>>(xi, conv_w, conv_b, xc_hi, xc_lo);
  gemm_mfma<0, 0><<<dim3(GM, 2), 256, 0, stream>>>(xc_hi, xc_lo, wx_hi, wx_lo, xdbl, nullptr, ML, NXx, 1024);
  gemm_nt<2><<<dim3(GM, DI / 128), 256, 0, stream>>>(xdbl, w_dt, b_dt, dt_l, ML, DI, DRr, NXx, DRr);
  transpose_k<0><<<dim3(157, 32, 2), tb, 0, stream>>>(dt_l, dtT, LL, DI, DI, (long long)LL * DI);
  transpose_recon_k<<<dim3(157, 32, 2), tb, 0, stream>>>(xc_hi, xc_lo, xcT, LL, DI, DI, (long long)LL * DI);
  transpose_k<1><<<dim3(157, 32, 2), tb, 0, stream>>>(z, szT, LL, DI, DI, (long long)LL * DI);
  scan_part_kernel<<<(BB * DI * NC) / 16, 256, 0, stream>>>(dtT, xcT, xdbl, A_log, part);
  scan_y_kernel<<<(BB * DI * NC) / 16, 256, 0, stream>>>(dtT, xcT, szT, xdbl, A_log, Dv, part, yT);
  cvt_split_kernel<<<512, 256, 0, stream>>>(w_out, wo_hi, wo_lo, 512 * 1024);
  transpose_split_k<<<dim3(32, 157, 2), tb, 0, stream>>>(yT, y_hi, y_lo, DI, LL, LL, (long long)LL * DI);
  gemm_mfma<1, 0><<<dim3(GM, 4), 256, 0, stream>>>(y_hi, y_lo, wo_hi, wo_lo, mbuf, nullptr, ML, DM, 1024);
  out_proj_kernel<<<ML / 4, 256, 0, stream>>>(mbuf, w_final, o);
  fc1_kernel<<<512, 256, 0, stream>>>(o, w_fc1, b_fc1, f1);
  fc2_kernel<<<256, 64, 0, stream>>>(f1, w_fc2, b_fc2, f2);
  fc34_kernel<<<1, 64, 0, stream>>>(f2, w_fc3, b_fc3, w_fc4, b_fc4, (float*)d_out);
}

// Round 7
// 1121.998 us; speedup vs baseline: 3.1471x; 1.1147x over previous
//
#include <hip/hip_runtime.h>

#define BB 2
#define LL 5000
#define DM 512
#define DI 1024
#define DSz 64
#define DRr 32
#define NXx 160
#define ML (BB*LL)
#define NC 25
#define LC 200

typedef short bf16x8 __attribute__((ext_vector_type(8)));
typedef float f32x4 __attribute__((ext_vector_type(4)));

__device__ __forceinline__ float siluf(float x) { return x / (1.0f + __expf(-x)); }
__device__ __forceinline__ float softplusf(float x) { return fmaxf(x, 0.0f) + log1pf(__expf(-fabsf(x))); }
__device__ __forceinline__ float seluf(float x) {
  const float sc = 1.0507009873554805f, al = 1.6732632423543772f;
  return x > 0.0f ? sc * x : sc * al * (__expf(x) - 1.0f);
}
__device__ __forceinline__ void bfsplit(float v, ushort& hi, ushort& lo) {
  unsigned u = __float_as_uint(v);
  unsigned h = (u + 0x7fffu + ((u >> 16) & 1u)) >> 16;
  hi = (ushort)h;
  float l = v - __uint_as_float(h << 16);
  unsigned ul = __float_as_uint(l);
  lo = (ushort)((ul + 0x7fffu + ((ul >> 16) & 1u)) >> 16);
}

// ---------------- weight fp32 -> (hi,lo) bf16 planes ----------------
__global__ __launch_bounds__(256) void cvt_split_kernel(
    const float* __restrict__ src, ushort* __restrict__ hi, ushort* __restrict__ lo, int n)
{
  int i = (blockIdx.x * 256 + threadIdx.x) * 4;
  if (i >= n) return;
  float4 v = *reinterpret_cast<const float4*>(src + i);
  ushort h0, l0, h1, l1, h2, l2, h3, l3;
  bfsplit(v.x, h0, l0); bfsplit(v.y, h1, l1);
  bfsplit(v.z, h2, l2); bfsplit(v.w, h3, l3);
  *reinterpret_cast<ushort4*>(hi + i) = make_ushort4(h0, h1, h2, h3);
  *reinterpret_cast<ushort4*>(lo + i) = make_ushort4(l0, l1, l2, l3);
}

// ---------------- k1: h[b,l,d] = sum_c x[b,c,l]*w_init[d,c], split output ----------------
__global__ __launch_bounds__(512) void init_h_split_kernel(
    const float* __restrict__ x, const float* __restrict__ w_init,
    ushort* __restrict__ hh, ushort* __restrict__ hl)
{
  int il = blockIdx.x;
  int b = il / LL, l = il - b * LL;
  int dd = threadIdx.x;
  const float* xp = x + (size_t)b * 12 * LL + l;
  float acc = 0.f;
#pragma unroll
  for (int c = 0; c < 12; ++c) acc = fmaf(xp[(size_t)c * LL], w_init[dd * 12 + c], acc);
  ushort h, lo; bfsplit(acc, h, lo);
  hh[(size_t)il * DM + dd] = h;
  hl[(size_t)il * DM + dd] = lo;
}

// ---------------- split-bf16 MFMA GEMM: C = act((Ahi+Alo)(Bhi+Blo)^T) ----------------
template<int ACT, int SPLITN>
__global__ __launch_bounds__(256) void gemm_mfma(
    const ushort* __restrict__ Ahi, const ushort* __restrict__ Alo,
    const ushort* __restrict__ Bhi, const ushort* __restrict__ Blo,
    float* __restrict__ C, float* __restrict__ C2, int M, int N, int K)
{
  __shared__ ushort lds[4][128][40];
  int tid = threadIdx.x;
  int i0 = blockIdx.x * 128, j0 = blockIdx.y * 128;
  int l = tid & 63, wid = tid >> 6;
  int wm = (wid >> 1) * 64, wn = (wid & 1) * 64;
  int lr = l & 15, lk = (l >> 4) * 8;
  int sr = tid >> 1, kb = (tid & 1) * 16;

  f32x4 acc[4][4];
#pragma unroll
  for (int m = 0; m < 4; ++m)
#pragma unroll
    for (int n = 0; n < 4; ++n) acc[m][n] = (f32x4){0.f, 0.f, 0.f, 0.f};

  const uint4 z4 = make_uint4(0u, 0u, 0u, 0u);
  for (int k0 = 0; k0 < K; k0 += 32) {
    __syncthreads();
    {
      int gi = i0 + sr, gj = j0 + sr;
      size_t aoff = (size_t)gi * K + k0 + kb;
      size_t boff = (size_t)gj * K + k0 + kb;
      uint4 a0 = z4, a1 = z4, b0 = z4, b1 = z4, c0 = z4, c1 = z4, d0 = z4, d1 = z4;
      if (gi < M) {
        a0 = *reinterpret_cast<const uint4*>(Ahi + aoff);
        a1 = *reinterpret_cast<const uint4*>(Ahi + aoff + 8);
        b0 = *reinterpret_cast<const uint4*>(Alo + aoff);
        b1 = *reinterpret_cast<const uint4*>(Alo + aoff + 8);
      }
      if (gj < N) {
        c0 = *reinterpret_cast<const uint4*>(Bhi + boff);
        c1 = *reinterpret_cast<const uint4*>(Bhi + boff + 8);
        d0 = *reinterpret_cast<const uint4*>(Blo + boff);
        d1 = *reinterpret_cast<const uint4*>(Blo + boff + 8);
      }
      *reinterpret_cast<uint4*>(&lds[0][sr][kb]) = a0;
      *reinterpret_cast<uint4*>(&lds[0][sr][kb + 8]) = a1;
      *reinterpret_cast<uint4*>(&lds[1][sr][kb]) = b0;
      *reinterpret_cast<uint4*>(&lds[1][sr][kb + 8]) = b1;
      *reinterpret_cast<uint4*>(&lds[2][sr][kb]) = c0;
      *reinterpret_cast<uint4*>(&lds[2][sr][kb + 8]) = c1;
      *reinterpret_cast<uint4*>(&lds[3][sr][kb]) = d0;
      *reinterpret_cast<uint4*>(&lds[3][sr][kb + 8]) = d1;
    }
    __syncthreads();
    bf16x8 ah[4], av[4], bh[4], bv[4];
#pragma unroll
    for (int m = 0; m < 4; ++m) {
      ah[m] = *reinterpret_cast<const bf16x8*>(&lds[0][wm + m * 16 + lr][lk]);
      av[m] = *reinterpret_cast<const bf16x8*>(&lds[1][wm + m * 16 + lr][lk]);
    }
#pragma unroll
    for (int n = 0; n < 4; ++n) {
      bh[n] = *reinterpret_cast<const bf16x8*>(&lds[2][wn + n * 16 + lr][lk]);
      bv[n] = *reinterpret_cast<const bf16x8*>(&lds[3][wn + n * 16 + lr][lk]);
    }
#pragma unroll
    for (int m = 0; m < 4; ++m)
#pragma unroll
      for (int n = 0; n < 4; ++n) {
        acc[m][n] = __builtin_amdgcn_mfma_f32_16x16x32_bf16(ah[m], bh[n], acc[m][n], 0, 0, 0);
        acc[m][n] = __builtin_amdgcn_mfma_f32_16x16x32_bf16(av[m], bh[n], acc[m][n], 0, 0, 0);
        acc[m][n] = __builtin_amdgcn_mfma_f32_16x16x32_bf16(ah[m], bv[n], acc[m][n], 0, 0, 0);
      }
  }

#pragma unroll
  for (int m = 0; m < 4; ++m) {
    int r0 = i0 + wm + m * 16 + (l >> 4) * 4;
#pragma unroll
    for (int n = 0; n < 4; ++n) {
      int gc = j0 + wn + n * 16 + lr;
      if (gc >= N) continue;
#pragma unroll
      for (int q = 0; q < 4; ++q) {
        int gi = r0 + q;
        if (gi >= M) continue;
        float r = acc[m][n][q];
        if (ACT == 1) r = seluf(r);
        if (SPLITN) {
          int half = N >> 1;
          if (gc < half) C[(size_t)gi * half + gc] = r;
          else C2[(size_t)gi * half + (gc - half)] = r;
        } else {
          C[(size_t)gi * N + gc] = r;
        }
      }
    }
  }
}

// ---------------- fused conv(k=4)+silu+split, ALSO writes xcT (LDS transpose) ----------------
__global__ __launch_bounds__(256) void conv_silu_split_t_kernel(
    const float* __restrict__ xi, const float* __restrict__ cw,
    const float* __restrict__ cb, ushort* __restrict__ xch, ushort* __restrict__ xcl,
    float* __restrict__ xcT)
{
  __shared__ float tile[32][33];
  int bz = blockIdx.z;
  int l0 = blockIdx.x * 32, d0 = blockIdx.y * 32;
  int tx = threadIdx.x, ty = threadIdx.y;
  int d = d0 + tx;
  float c0 = cw[d * 4 + 0], c1 = cw[d * 4 + 1], c2 = cw[d * 4 + 2], c3 = cw[d * 4 + 3];
  float cbv = cb[d];
#pragma unroll
  for (int i = ty; i < 32; i += 8) {
    int l = l0 + i;
    if (l < LL) {
      size_t il = (size_t)bz * LL + l;
      float acc = cbv;
      if (l >= 3) acc = fmaf(xi[(il - 3) * DI + d], c0, acc);
      if (l >= 2) acc = fmaf(xi[(il - 2) * DI + d], c1, acc);
      if (l >= 1) acc = fmaf(xi[(il - 1) * DI + d], c2, acc);
      acc = fmaf(xi[il * DI + d], c3, acc);
      float v = siluf(acc);
      ushort h, lo; bfsplit(v, h, lo);
      xch[il * DI + d] = h;
      xcl[il * DI + d] = lo;
      tile[i][tx] = v;
    }
  }
  __syncthreads();
#pragma unroll
  for (int i = ty; i < 32; i += 8) {
    int dd = d0 + i, l = l0 + tx;
    if (l < LL) xcT[((size_t)bz * DI + dd) * LL + l] = tile[tx][i];
  }
}

// ---------------- fused dt projection (K=32) + softplus, writes dtT directly ----------------
__global__ __launch_bounds__(256) void dtproj_t_kernel(
    const float* __restrict__ xdbl, const float* __restrict__ w_dt,
    const float* __restrict__ b_dt, float* __restrict__ dtT)
{
  __shared__ float wlds[16][32];
  __shared__ float blds[16];
  int bz = blockIdx.z;
  int l0 = blockIdx.x * 64, d0 = blockIdx.y * 16;
  int tid = threadIdx.x;
  for (int idx = tid; idx < 512; idx += 256) {
    int r = idx >> 5, cc = idx & 31;
    wlds[r][cc] = w_dt[(size_t)(d0 + r) * DRr + cc];
  }
  if (tid < 16) blds[tid] = b_dt[d0 + tid];
  __syncthreads();
  int lx = tid & 63, ty = tid >> 6;
  int l = l0 + lx;
  if (l >= LL) return;
  const float* xr = xdbl + ((size_t)bz * LL + l) * NXx;
  float xv[32];
#pragma unroll
  for (int q = 0; q < 8; ++q) {
    float4 v = *reinterpret_cast<const float4*>(xr + 4 * q);
    xv[4 * q] = v.x; xv[4 * q + 1] = v.y; xv[4 * q + 2] = v.z; xv[4 * q + 3] = v.w;
  }
#pragma unroll
  for (int k = 0; k < 4; ++k) {
    int dd = ty * 4 + k;
    float acc = blds[dd];
#pragma unroll
    for (int kk = 0; kk < 32; ++kk) acc = fmaf(xv[kk], wlds[dd][kk], acc);
    dtT[((size_t)bz * DI + d0 + dd) * LL + l] = softplusf(acc);
  }
}

// ---------------- transpose with silu (for z -> szT) ----------------
template<int ACT>
__global__ __launch_bounds__(256) void transpose_k(
    const float* __restrict__ in, float* __restrict__ out,
    int R, int Cc, int ldin, long long bstr)
{
  __shared__ float tile[32][33];
  const float* ip = in + (size_t)blockIdx.z * bstr;
  float* op = out + (size_t)blockIdx.z * bstr;
  int r0 = blockIdx.x * 32, c0 = blockIdx.y * 32;
  int tx = threadIdx.x, ty2 = threadIdx.y;
#pragma unroll
  for (int i = ty2; i < 32; i += 8) {
    int r = r0 + i, c = c0 + tx;
    if (r < R && c < Cc) {
      float v = ip[(size_t)r * ldin + c];
      if (ACT == 1) v = siluf(v);
      tile[i][tx] = v;
    }
  }
  __syncthreads();
#pragma unroll
  for (int i = ty2; i < 32; i += 8) {
    int c = c0 + i, r = r0 + tx;
    if (r < R && c < Cc) op[(size_t)c * R + r] = tile[tx][i];
  }
}

// fp32 -> hi/lo transpose (for y)
__global__ __launch_bounds__(256) void transpose_split_k(
    const float* __restrict__ in, ushort* __restrict__ outhi, ushort* __restrict__ outlo,
    int R, int Cc, int ldin, long long bstr)
{
  __shared__ float tile[32][33];
  const float* ip = in + (size_t)blockIdx.z * bstr;
  ushort* oph = outhi + (size_t)blockIdx.z * bstr;
  ushort* opl = outlo + (size_t)blockIdx.z * bstr;
  int r0 = blockIdx.x * 32, c0 = blockIdx.y * 32;
  int tx = threadIdx.x, ty2 = threadIdx.y;
#pragma unroll
  for (int i = ty2; i < 32; i += 8) {
    int r = r0 + i, c = c0 + tx;
    if (r < R && c < Cc) tile[i][tx] = ip[(size_t)r * ldin + c];
  }
  __syncthreads();
#pragma unroll
  for (int i = ty2; i < 32; i += 8) {
    int c = c0 + i, r = r0 + tx;
    if (r < R && c < Cc) {
      ushort h, lo; bfsplit(tile[tx][i], h, lo);
      size_t idx = (size_t)c * R + r;
      oph[idx] = h; opl[idx] = lo;
    }
  }
}

// ---------------- selective scan, chunked 2-stage, 4-states-per-lane ----------------
// exp2 trick: Ace = -exp(A_log)*log2(e); a = exp2(dtv*Ace)  (bare v_exp_f32)
#define L2E 1.44269504088896f

__global__ __launch_bounds__(256) void scan_part_kernel(
    const float* __restrict__ dtT, const float* __restrict__ uT,
    const float* __restrict__ xdbl, const float* __restrict__ A_log,
    float2* __restrict__ part)
{
  int task = (blockIdx.x * 256 + threadIdx.x) >> 4;
  int j = threadIdx.x & 15;
  int bd = task / NC, c = task - bd * NC;
  int b = bd >> 10, d = bd & (DI - 1);
  float4 Al = *reinterpret_cast<const float4*>(A_log + d * DSz + 4 * j);
  float Ac0 = -__expf(Al.x) * L2E, Ac1 = -__expf(Al.y) * L2E;
  float Ac2 = -__expf(Al.z) * L2E, Ac3 = -__expf(Al.w) * L2E;
  size_t base = (size_t)bd * LL + c * LC;
  const float4* pdt4 = reinterpret_cast<const float4*>(dtT + base);
  const float4* pu4 = reinterpret_cast<const float4*>(uT + base);
  const float4* pB4 = reinterpret_cast<const float4*>(
      xdbl + ((size_t)b * LL + c * LC) * NXx + DRr) + j;
  float h0 = 0.f, h1 = 0.f, h2 = 0.f, h3 = 0.f;
  float ap0 = 1.f, ap1 = 1.f, ap2 = 1.f, ap3 = 1.f;
  for (int t0 = 0; t0 < LC; t0 += 4) {
    float4 dt4 = pdt4[t0 >> 2];
    float4 u4 = pu4[t0 >> 2];
    float dts[4] = {dt4.x, dt4.y, dt4.z, dt4.w};
    float us[4] = {u4.x, u4.y, u4.z, u4.w};
#pragma unroll
    for (int i = 0; i < 4; ++i) {
      float dtv = dts[i], u = us[i];
      float4 Bv = pB4[0]; pB4 += NXx / 4;
      float du = dtv * u;
      float a0 = exp2f(dtv * Ac0); h0 = fmaf(a0, h0, du * Bv.x); ap0 *= a0;
      float a1 = exp2f(dtv * Ac1); h1 = fmaf(a1, h1, du * Bv.y); ap1 *= a1;
      float a2 = exp2f(dtv * Ac2); h2 = fmaf(a2, h2, du * Bv.z); ap2 *= a2;
      float a3 = exp2f(dtv * Ac3); h3 = fmaf(a3, h3, du * Bv.w); ap3 *= a3;
    }
  }
  float4* pw = reinterpret_cast<float4*>(part + (size_t)task * DSz + 4 * j);
  pw[0] = make_float4(ap0, h0, ap1, h1);
  pw[1] = make_float4(ap2, h2, ap3, h3);
}

__global__ __launch_bounds__(256) void scan_y_kernel(
    const float* __restrict__ dtT, const float* __restrict__ uT,
    const float* __restrict__ szT, const float* __restrict__ xdbl,
    const float* __restrict__ A_log, const float* __restrict__ Dv,
    const float2* __restrict__ part, float* __restrict__ yT)
{
  int task = (blockIdx.x * 256 + threadIdx.x) >> 4;
  int j = threadIdx.x & 15;
  int bd = task / NC, c = task - bd * NC;
  int b = bd >> 10, d = bd & (DI - 1);
  float4 Al = *reinterpret_cast<const float4*>(A_log + d * DSz + 4 * j);
  float Ac0 = -__expf(Al.x) * L2E, Ac1 = -__expf(Al.y) * L2E;
  float Ac2 = -__expf(Al.z) * L2E, Ac3 = -__expf(Al.w) * L2E;
  float Dd = Dv[d];

  float h0 = 0.f, h1 = 0.f, h2 = 0.f, h3 = 0.f;
  const float4* pp = reinterpret_cast<const float4*>(part + (size_t)bd * NC * DSz) + 2 * j;
  for (int p = 0; p < c; ++p) {
    float4 v01 = pp[(size_t)p * (DSz / 2)];
    float4 v23 = pp[(size_t)p * (DSz / 2) + 1];
    h0 = fmaf(v01.x, h0, v01.y);
    h1 = fmaf(v01.z, h1, v01.w);
    h2 = fmaf(v23.x, h2, v23.y);
    h3 = fmaf(v23.z, h3, v23.w);
  }

  size_t base = (size_t)bd * LL + c * LC;
  const float4* pdt4 = reinterpret_cast<const float4*>(dtT + base);
  const float4* pu4 = reinterpret_cast<const float4*>(uT + base);
  const float4* psz4 = reinterpret_cast<const float4*>(szT + base);
  float4* py4 = reinterpret_cast<float4*>(yT + base);
  const float4* pB4 = reinterpret_cast<const float4*>(
      xdbl + ((size_t)b * LL + c * LC) * NXx + DRr) + j;

  for (int t0 = 0; t0 < LC; t0 += 8) {
    float4 dA = pdt4[0], dB = pdt4[1]; pdt4 += 2;
    float4 uA = pu4[0], uB = pu4[1]; pu4 += 2;
    float4 sA = psz4[0], sB = psz4[1]; psz4 += 2;
    float dts[8] = {dA.x, dA.y, dA.z, dA.w, dB.x, dB.y, dB.z, dB.w};
    float us[8]  = {uA.x, uA.y, uA.z, uA.w, uB.x, uB.y, uB.z, uB.w};
    float ss[8]  = {sA.x, sA.y, sA.z, sA.w, sB.x, sB.y, sB.z, sB.w};
    float pr[8];
#pragma unroll
    for (int i = 0; i < 8; ++i) {
      float dtv = dts[i], u = us[i];
      float4 Bv = pB4[0];
      float4 Cv = pB4[DSz / 4];
      pB4 += NXx / 4;
      float du = dtv * u;
      float a0 = exp2f(dtv * Ac0); h0 = fmaf(a0, h0, du * Bv.x);
      float a1 = exp2f(dtv * Ac1); h1 = fmaf(a1, h1, du * Bv.y);
      float a2 = exp2f(dtv * Ac2); h2 = fmaf(a2, h2, du * Bv.z);
      float a3 = exp2f(dtv * Ac3); h3 = fmaf(a3, h3, du * Bv.w);
      pr[i] = fmaf(h3, Cv.w, fmaf(h2, Cv.z, fmaf(h1, Cv.y, h0 * Cv.x)));
    }
#pragma unroll
    for (int mm = 8; mm >= 1; mm >>= 1) {
#pragma unroll
      for (int i = 0; i < 8; ++i) pr[i] += __shfl_xor(pr[i], mm, 64);
    }
    if (j == 0) {
      float4 o0 = make_float4(fmaf(us[0], Dd, pr[0]) * ss[0], fmaf(us[1], Dd, pr[1]) * ss[1],
                              fmaf(us[2], Dd, pr[2]) * ss[2], fmaf(us[3], Dd, pr[3]) * ss[3]);
      float4 o1 = make_float4(fmaf(us[4], Dd, pr[4]) * ss[4], fmaf(us[5], Dd, pr[5]) * ss[5],
                              fmaf(us[6], Dd, pr[6]) * ss[6], fmaf(us[7], Dd, pr[7]) * ss[7]);
      py4[0] = o0; py4[1] = o1;
    }
    py4 += 2;
  }
}

// ---------------- o[b,c,l] = sum_j m[b,l,j]*w_final[c,j]; wave per (b,l) ----------------
__global__ __launch_bounds__(256) void out_proj_kernel(
    const float* __restrict__ m, const float* __restrict__ wf, float* __restrict__ o)
{
  int row = blockIdx.x * 4 + (threadIdx.x >> 6);
  int lane = threadIdx.x & 63;
  int b = row / LL, l = row - b * LL;
  const float* mp = m + (size_t)row * DM;
  float p[12];
#pragma unroll
  for (int c = 0; c < 12; ++c) p[c] = 0.f;
  for (int j0 = 0; j0 < DM; j0 += 64) {
    float mv = mp[j0 + lane];
#pragma unroll
    for (int c = 0; c < 12; ++c) p[c] = fmaf(mv, wf[c * DM + j0 + lane], p[c]);
  }
#pragma unroll
  for (int c = 0; c < 12; ++c) {
    float v = p[c];
#pragma unroll
    for (int mm = 32; mm >= 1; mm >>= 1) v += __shfl_xor(v, mm, 64);
    if (lane == 0) o[(size_t)b * 60000 + c * LL + l] = v;
  }
}

// ---------------- fc chain ----------------
__global__ __launch_bounds__(256) void fc1_kernel(
    const float* __restrict__ o, const float* __restrict__ w1,
    const float* __restrict__ b1, float* __restrict__ f1)
{
  int i = blockIdx.x;
  int tid = threadIdx.x;
  const float* wr = w1 + (size_t)i * 60000;
  float a0 = 0.f, a1 = 0.f;
  for (int idx = tid; idx < 60000; idx += 256) {
    float w = wr[idx];
    a0 = fmaf(o[idx], w, a0);
    a1 = fmaf(o[60000 + idx], w, a1);
  }
#pragma unroll
  for (int mm = 32; mm >= 1; mm >>= 1) { a0 += __shfl_xor(a0, mm, 64); a1 += __shfl_xor(a1, mm, 64); }
  __shared__ float r0[4], r1[4];
  int w4 = tid >> 6;
  if ((tid & 63) == 0) { r0[w4] = a0; r1[w4] = a1; }
  __syncthreads();
  if (tid == 0) {
    f1[i] = r0[0] + r0[1] + r0[2] + r0[3] + b1[i];
    f1[512 + i] = r1[0] + r1[1] + r1[2] + r1[3] + b1[i];
  }
}

__global__ __launch_bounds__(64) void fc2_kernel(
    const float* __restrict__ f1, const float* __restrict__ w2,
    const float* __restrict__ b2, float* __restrict__ f2)
{
  int i = blockIdx.x;
  int lane = threadIdx.x;
  const float* wr = w2 + (size_t)i * 512;
  float a0 = 0.f, a1 = 0.f;
  for (int k = lane; k < 512; k += 64) {
    float w = wr[k];
    a0 = fmaf(f1[k], w, a0);
    a1 = fmaf(f1[512 + k], w, a1);
  }
#pragma unroll
  for (int mm = 32; mm >= 1; mm >>= 1) { a0 += __shfl_xor(a0, mm, 64); a1 += __shfl_xor(a1, mm, 64); }
  if (lane == 0) { f2[i] = a0 + b2[i]; f2[256 + i] = a1 + b2[i]; }
}

__global__ __launch_bounds__(64) void fc34_kernel(
    const float* __restrict__ f2, const float* __restrict__ w3, const float* __restrict__ b3,
    const float* __restrict__ w4, const float* __restrict__ b4, float* __restrict__ outp)
{
  __shared__ float f3[128];
  int t = threadIdx.x;
  float a0 = 0.f, a1 = 0.f;
  for (int k = 0; k < 256; ++k) {
    float w = w3[t * 256 + k];
    a0 = fmaf(f2[k], w, a0);
    a1 = fmaf(f2[256 + k], w, a1);
  }
  f3[t] = a0 + b3[t];
  f3[64 + t] = a1 + b3[t];
  __syncthreads();
  if (t < 16) {
    int b = t >> 3, i = t & 7;
    float a = b4[i];
    for (int k = 0; k < 64; ++k) a = fmaf(f3[b * 64 + k], w4[i * 64 + k], a);
    outp[b * 8 + i] = a;
  }
}

extern "C" void kernel_launch(void* const* d_in, const int* in_sizes, int n_in,
                              void* d_out, int out_size, void* d_ws, size_t ws_size,
                              hipStream_t stream)
{
  const float* x       = (const float*)d_in[0];
  const float* w_init  = (const float*)d_in[1];
  const float* w_final = (const float*)d_in[2];
  const float* w_in    = (const float*)d_in[3];
  const float* conv_w  = (const float*)d_in[4];
  const float* conv_b  = (const float*)d_in[5];
  const float* w_xproj = (const float*)d_in[6];
  const float* w_dt    = (const float*)d_in[7];
  const float* b_dt    = (const float*)d_in[8];
  const float* A_log   = (const float*)d_in[9];
  const float* Dv      = (const float*)d_in[10];
  const float* w_out   = (const float*)d_in[11];
  const float* w_fc1   = (const float*)d_in[12];
  const float* b_fc1   = (const float*)d_in[13];
  const float* w_fc2   = (const float*)d_in[14];
  const float* b_fc2   = (const float*)d_in[15];
  const float* w_fc3   = (const float*)d_in[16];
  const float* b_fc3   = (const float*)d_in[17];
  const float* w_fc4   = (const float*)d_in[18];
  const float* b_fc4   = (const float*)d_in[19];

  float* ws = (float*)d_ws;
  const size_t S7 = 0;                               // h_hi/h_lo -> later mbuf
  const size_t S1 = S7 + (size_t)ML * DM;            // xi -> yT
  const size_t S2 = S1 + (size_t)ML * DI;            // z -> part -> y_hi/y_lo
  const size_t S3 = S2 + (size_t)ML * DI;            // xc_hi/xc_lo -> szT
  const size_t S4 = S3 + (size_t)ML * DI;            // wi/wx weights -> dtT
  const size_t S5 = S4 + (size_t)ML * DI;            // xcT -> wo hi/lo
  const size_t S8 = S5 + (size_t)ML * DI;            // xdbl
  const size_t S9 = S8 + (size_t)ML * NXx;           // o
  const size_t SF1 = S9 + 120000;
  const size_t SF2 = SF1 + 1024;

  ushort* h_hi = (ushort*)(ws + S7);
  ushort* h_lo = h_hi + (size_t)ML * DM;
  float*  xi   = ws + S1;
  float*  z    = ws + S2;
  ushort* xc_hi = (ushort*)(ws + S3);
  ushort* xc_lo = xc_hi + (size_t)ML * DI;
  float*  dtT  = ws + S4;
  float*  xcT  = ws + S5;
  float*  xdbl = ws + S8;
  float*  szT  = ws + S3;
  float2* part = (float2*)(ws + S2);
  float*  yT   = ws + S1;
  ushort* y_hi = (ushort*)(ws + S2);
  ushort* y_lo = y_hi + (size_t)ML * DI;
  float*  mbuf = ws + S7;
  float*  o    = ws + S9;
  float*  f1   = ws + SF1;
  float*  f2   = ws + SF2;

  // wi/wx weights live in the dtT slot (dead exactly when dtproj_t writes dtT)
  ushort* wb    = (ushort*)(ws + S4);
  ushort* wi_hi = wb;
  ushort* wi_lo = wb + (size_t)2048 * 512;
  ushort* wx_hi = wb + (size_t)2 * 2048 * 512;
  ushort* wx_lo = wx_hi + (size_t)160 * 1024;
  // wo lives in the xcT slot (dead after scan_y)
  ushort* wo_hi = (ushort*)(ws + S5);
  ushort* wo_lo = wo_hi + (size_t)512 * 1024;

  const int GM = (ML + 127) / 128;   // 79
  dim3 tb(32, 8);

  cvt_split_kernel<<<1024, 256, 0, stream>>>(w_in, wi_hi, wi_lo, 2048 * 512);
  cvt_split_kernel<<<160, 256, 0, stream>>>(w_xproj, wx_hi, wx_lo, 160 * 1024);
  init_h_split_kernel<<<ML, 512, 0, stream>>>(x, w_init, h_hi, h_lo);
  gemm_mfma<0, 1><<<dim3(GM, 16), 256, 0, stream>>>(h_hi, h_lo, wi_hi, wi_lo, xi, z, ML, 2048, 512);
  conv_silu_split_t_kernel<<<dim3(157, 32, 2), tb, 0, stream>>>(xi, conv_w, conv_b, xc_hi, xc_lo, xcT);
  gemm_mfma<0, 0><<<dim3(GM, 2), 256, 0, stream>>>(xc_hi, xc_lo, wx_hi, wx_lo, xdbl, nullptr, ML, NXx, 1024);
  dtproj_t_kernel<<<dim3(79, 64, 2), 256, 0, stream>>>(xdbl, w_dt, b_dt, dtT);
  transpose_k<1><<<dim3(157, 32, 2), tb, 0, stream>>>(z, szT, LL, DI, DI, (long long)LL * DI);
  scan_part_kernel<<<(BB * DI * NC) / 16, 256, 0, stream>>>(dtT, xcT, xdbl, A_log, part);
  scan_y_kernel<<<(BB * DI * NC) / 16, 256, 0, stream>>>(dtT, xcT, szT, xdbl, A_log, Dv, part, yT);
  cvt_split_kernel<<<512, 256, 0, stream>>>(w_out, wo_hi, wo_lo, 512 * 1024);
  transpose_split_k<<<dim3(32, 157, 2), tb, 0, stream>>>(yT, y_hi, y_lo, DI, LL, LL, (long long)LL * DI);
  gemm_mfma<1, 0><<<dim3(GM, 4), 256, 0, stream>>>(y_hi, y_lo, wo_hi, wo_lo, mbuf, nullptr, ML, DM, 1024);
  out_proj_kernel<<<ML / 4, 256, 0, stream>>>(mbuf, w_final, o);
  fc1_kernel<<<512, 256, 0, stream>>>(o, w_fc1, b_fc1, f1);
  fc2_kernel<<<256, 64, 0, stream>>>(f1, w_fc2, b_fc2, f2);
  fc34_kernel<<<1, 64, 0, stream>>>(f2, w_fc3, b_fc3, w_fc4, b_fc4, (float*)d_out);
}